// Round 25
// baseline (379.513 us; speedup 1.0000x reference)
//
#include <hip/hip_runtime.h>
#include <hip/hip_fp16.h>

#define NN 100000
#define NE 1600000
#define DIM 300
#define HID 128
#define NC 20
#define NG 512
#define NBK 196        // buckets of 512 nodes
#define BCH 4096       // edges per scatter chunk

typedef _Float16 h8 __attribute__((ext_vector_type(8)));
typedef float f4 __attribute__((ext_vector_type(4)));

union pack16 { float4 v; __half2 h2[4]; };

__device__ __forceinline__ __half tohalf(float v) {
  if (!(v == v)) v = 0.f;
  v = fminf(fmaxf(v, -60000.f), 60000.f);
  return __float2half(v);
}

__device__ __forceinline__ float load_x(const void* xraw, size_t o, int mode) {
  float v;
  if (mode == 2) v = ((const float*)xraw)[o];
  else {
    unsigned short u = ((const unsigned short*)xraw)[o];
    if (mode == 1) { union { unsigned w; float f; } c; c.w = ((unsigned)u) << 16; v = c.f; }
    else { union { unsigned short s; _Float16 h; } c; c.s = u; v = (float)c.h; }
  }
  if (!(v == v)) v = 0.f;
  return fminf(fmaxf(v, -1e4f), 1e4f);
}

__device__ __forceinline__ void cvt4(const void* Ain, size_t off, int mode, _Float16* o) {
  if (mode == 2) {
    float4 fv = *(const float4*)((const float*)Ain + off);
    o[0] = (_Float16)fv.x; o[1] = (_Float16)fv.y; o[2] = (_Float16)fv.z; o[3] = (_Float16)fv.w;
  } else {
    uint2 u = *(const uint2*)((const unsigned short*)Ain + off);
    unsigned short s0 = u.x & 0xFFFF, s1 = u.x >> 16, s2 = u.y & 0xFFFF, s3 = u.y >> 16;
    if (mode == 1) {
      union { unsigned w; float f; } c0, c1, c2, c3;
      c0.w = ((unsigned)s0) << 16; c1.w = ((unsigned)s1) << 16;
      c2.w = ((unsigned)s2) << 16; c3.w = ((unsigned)s3) << 16;
      o[0] = (_Float16)c0.f; o[1] = (_Float16)c1.f; o[2] = (_Float16)c2.f; o[3] = (_Float16)c3.f;
    } else {
      union { unsigned short s; _Float16 h; } d0, d1, d2, d3;
      d0.s = s0; d1.s = s1; d2.s = s2; d3.s = s3;
      o[0] = d0.h; o[1] = d1.h; o[2] = d2.h; o[3] = d3.h;
    }
  }
}

// ============ merged probe + weight-prep kernel ============

__global__ void k_probe(const unsigned short* __restrict__ xu,
                        const unsigned* __restrict__ Araw, const unsigned* __restrict__ Braw,
                        const int* __restrict__ e32,
                        const float* __restrict__ W1, const float* __restrict__ W2,
                        _Float16* __restrict__ w1f, _Float16* __restrict__ w2f,
                        unsigned* __restrict__ diag) {
  int b = blockIdx.x, t = threadIdx.x;
  if (b < 96) {
    int mode = b % 3, chunk = b / 3;
    float m = 0.f;
    if (mode == 0) {
      int base = chunk * 16384;
      for (int j = t; j < 16384; j += 256) {
        union { unsigned short s; _Float16 h; } c; c.s = xu[base + j];
        float v = fabsf((float)c.h);
        if (v == v && v < 65000.f) m = fmaxf(m, v);
      }
    } else if (mode == 1) {
      int base = chunk * 16384;
      for (int j = t; j < 16384; j += 256) {
        union { unsigned w; float f; } c; c.w = ((unsigned)xu[base + j]) << 16;
        float v = fabsf(c.f);
        if (v == v && v < 1e30f) m = fmaxf(m, v);
      }
    } else {
      const float* xf = (const float*)xu;
      int base = chunk * 8192;
      for (int j = t; j < 8192; j += 256) {
        float v = fabsf(xf[base + j]);
        if (v == v && v < 1e30f) m = fmaxf(m, v);
      }
    }
    for (int off = 32; off; off >>= 1) m = fmaxf(m, __shfl_xor(m, off));
    if ((t & 63) == 0) atomicMax(&diag[20 + mode], __float_as_uint(m));
  } else if (b == 96 || b == 97) {
    __shared__ unsigned red[256];
    const unsigned* p = (b == 96) ? Araw : Braw;
    unsigned m = 0;
    for (int j = t; j < 25000; j += 256) m = max(m, p[j]);
    red[t] = m; __syncthreads();
    for (int off = 128; off; off >>= 1) { if (t < off) red[t] = max(red[t], red[t + off]); __syncthreads(); }
    if (t == 0) diag[(b == 96) ? 24 : 25] = red[0];
  } else if (b < 102) {
    int i = (b - 98) * 256 + t;
    unsigned z = 0;
    for (; i < 50000; i += 1024) if (e32[2 * i + 1] == 0) z++;
    for (int off = 32; off; off >>= 1) z += __shfl_xor(z, off);
    if ((t & 63) == 0) atomicAdd(&diag[26], z);
  } else {
    int idx = (b - 102) * 256 + t;
    const int S1 = 10 * 8 * 64 * 8;  // 40960
    const int S2 = 4 * 8 * 64 * 8;   // 16384
    if (idx < S1) {
      int j = idx & 7, l = (idx >> 3) & 63, nt = (idx >> 9) & 7, kc = idx >> 12;
      int k = kc * 32 + ((l >> 4) << 3) + j;
      int n = nt * 16 + (l & 15);
      w1f[idx] = (k < DIM) ? (_Float16)W1[k * HID + n] : (_Float16)0.f;
    } else if (idx < S1 + S2) {
      int q = idx - S1;
      int j = q & 7, l = (q >> 3) & 63, nt = (q >> 9) & 7, kc = q >> 12;
      int k = kc * 32 + ((l >> 4) << 3) + j;
      int n = nt * 16 + (l & 15);
      w2f[q] = (_Float16)W2[k * HID + n];
    }
  }
}

// ============ merged setup: decide flags + gstart + bcnt zero ============

__global__ void k_setup(const unsigned* __restrict__ diag, int* __restrict__ flags,
                        const int* __restrict__ A, const int* __restrict__ B,
                        int* __restrict__ bcnt, int* __restrict__ gstart) {
  __shared__ int sflags[8];
  int t = threadIdx.x;
  if (t == 0) {
    float M16 = __uint_as_float(diag[20]);
    float M32 = __uint_as_float(diag[21]);
    float Mf  = __uint_as_float(diag[22]);
    int xmode = 3;
    if      (Mf  > 3.f && Mf  < 8.f) xmode = 2;
    else if (M32 > 3.f && M32 < 8.f) xmode = 1;
    else if (M16 > 3.f && M16 < 8.f) xmode = 0;
    unsigned uA = diag[24], uB = diag[25];
    bool Ab = (uA >= 32u && uA < 1024u), Bb = (uB >= 32u && uB < 1024u);
    int swap = -1;
    if (Ab && !Bb) swap = 0;
    else if (Bb && !Ab) swap = 1;
    int mint = -1;
    if (swap >= 0) {
      unsigned um = (swap == 0) ? uB : uA;
      if (um <= 1u) mint = 1;
      else if (um >= 65536u) mint = 0;
    }
    sflags[0] = xmode;
    sflags[1] = (mint == 1) ? 1 : 0;
    sflags[2] = (swap == 1) ? 1 : 0;
    sflags[3] = (diag[26] >= 49990u) ? 1 : 0;
    sflags[4] = (swap >= 0 && mint >= 0) ? 1 : 0;
    #pragma unroll
    for (int j = 0; j < 5; j++) flags[j] = sflags[j];
  }
  __syncthreads();
  const int* batch = sflags[2] ? B : A;
  if (t <= NG) {
    if (t == NG) gstart[NG] = NN;
    else {
      int lo = 0, hi = NN;
      while (lo < hi) { int mid = (lo + hi) >> 1; if (batch[mid] < t) lo = mid + 1; else hi = mid; }
      gstart[t] = lo;
    }
  }
  if (t < NBK) bcnt[t] = 0;
}

// ================= bucketed CSR build (hist + last-block scan) =================

__global__ void k_bhist(const int* __restrict__ e32, const int* __restrict__ flags,
                        int* __restrict__ bcnt, int* __restrict__ boff,
                        int* __restrict__ bcur, unsigned* __restrict__ done) {
  __shared__ int hist[NBK];
  int e64 = flags[3];
  int t = threadIdx.x;
  for (int j = t; j < NBK; j += 256) hist[j] = 0;
  __syncthreads();
  int i = blockIdx.x * blockDim.x + t;
  int stride = gridDim.x * blockDim.x;
  for (; i < NE; i += stride) {
    int s = e64 ? e32[2 * i] : e32[i];
    int d = e64 ? e32[2 * NE + 2 * i] : e32[NE + i];
    if ((unsigned)s < (unsigned)NN && (unsigned)d < (unsigned)NN)
      atomicAdd(&hist[d >> 9], 1);
  }
  __syncthreads();
  for (int j = t; j < NBK; j += 256) if (hist[j]) atomicAdd(&bcnt[j], hist[j]);
  __threadfence();
  __syncthreads();
  if (t == 0) {
    if (atomicAdd(done, 1u) == gridDim.x - 1) {
      int run = 0;
      for (int j = 0; j < NBK; j++) { boff[j] = run; bcur[j] = run; run += bcnt[j]; }
      boff[NBK] = run;
    }
  }
}

__global__ __launch_bounds__(256)
void k_bscatter(const int* __restrict__ e32, const int* __restrict__ flags,
                int* __restrict__ bcur, unsigned* __restrict__ ebuf) {
  __shared__ uint2 stage[BCH];           // 32 KB
  __shared__ int hist[NBK];
  __shared__ int lbase[NBK];
  __shared__ int lcur[NBK];
  int e64 = flags[3];
  int t = threadIdx.x;
  for (int j = t; j < NBK; j += 256) { hist[j] = 0; lcur[j] = 0; }
  __syncthreads();
  int start = blockIdx.x * BCH;
  int n = NE - start; if (n > BCH) n = BCH;
  for (int i = t; i < n; i += 256) {
    int idx = start + i;
    int s = e64 ? e32[2 * idx] : e32[idx];
    int d = e64 ? e32[2 * NE + 2 * idx] : e32[NE + idx];
    bool ok = ((unsigned)s < (unsigned)NN) && ((unsigned)d < (unsigned)NN);
    stage[i] = make_uint2(ok ? (unsigned)s : 0xFFFFFFFFu, (unsigned)(ok ? d : 0));
    if (ok) atomicAdd(&hist[d >> 9], 1);
  }
  __syncthreads();
  for (int j = t; j < NBK; j += 256) if (hist[j] > 0) lbase[j] = atomicAdd(&bcur[j], hist[j]);
  __syncthreads();
  for (int i = t; i < n; i += 256) {
    unsigned s = stage[i].x;
    if (s == 0xFFFFFFFFu) continue;
    int d = (int)stage[i].y;
    int b = d >> 9;
    int o = atomicAdd(&lcur[b], 1);
    ebuf[lbase[b] + o] = (s << 9) | (unsigned)(d & 511);
  }
}

__global__ __launch_bounds__(256)
void k_bfinal(const unsigned* __restrict__ ebuf, const int* __restrict__ boff,
              int* __restrict__ row_off, float* __restrict__ dinv, int* __restrict__ csr) {
  __shared__ int ldeg[512];
  __shared__ int lcur[512];
  int b = blockIdx.x, t = threadIdx.x;
  int base = b * 512;
  int nn = NN - base; if (nn > 512) nn = 512;
  for (int j = t; j < 512; j += 256) ldeg[j] = 0;
  __syncthreads();
  int s0 = boff[b], s1 = boff[b + 1];
  for (int e = s0 + t; e < s1; e += 256) atomicAdd(&ldeg[ebuf[e] & 511], 1);
  __syncthreads();
  if (t == 0) {
    int run = s0;
    for (int i = 0; i < nn; i++) { lcur[i] = run; row_off[base + i] = run; run += ldeg[i]; }
    if (b == gridDim.x - 1) row_off[NN] = run;
  }
  __syncthreads();
  for (int j = t; j < nn; j += 256) dinv[base + j] = rsqrtf((float)ldeg[j] + 1.0f);
  for (int e = s0 + t; e < s1; e += 256) {
    unsigned v = ebuf[e];
    int p = atomicAdd(&lcur[v & 511], 1);
    csr[p] = (int)(v >> 9);
  }
}

// ============ GEMM1: 512-thread blocks (8 waves, 1 nt each), two-pass K-split ============

#define XS1 168

__global__ __launch_bounds__(512)
void k_gemm1_mfma(const void* __restrict__ Ain, const _Float16* __restrict__ bfrag,
                  const float* __restrict__ dinv, const int* __restrict__ flags,
                  __half* __restrict__ outg) {
  __shared__ _Float16 xs[64 * XS1];   // 21504 B
  const int mode = flags[0] & 3;
  int tid = threadIdx.x;
  int w = tid >> 6, l = tid & 63;
  int rowbase = blockIdx.x * 64;
  int k0base = (l >> 4) << 3;
  int cb = l & 15;

  f4 acc[4];
  f4 zero = {0.f, 0.f, 0.f, 0.f};
  #pragma unroll
  for (int rg = 0; rg < 4; rg++) acc[rg] = zero;

  #pragma unroll
  for (int it = 0; it < 5; it++) {
    int c = tid + it * 512;
    int rl = c / 40, kk = (c - rl * 40) * 4;
    int r = rowbase + rl;
    _Float16 o[4] = {0, 0, 0, 0};
    if (r < NN) cvt4(Ain, (size_t)r * DIM + kk, mode, o);
    _Float16* p = &xs[rl * XS1 + kk];
    p[0] = o[0]; p[1] = o[1]; p[2] = o[2]; p[3] = o[3];
  }
  __syncthreads();
  #pragma unroll
  for (int kc = 0; kc < 5; kc++) {
    int ko = kc * 32 + k0base;
    h8 a0 = *(const h8*)&xs[(0 * 16 + cb) * XS1 + ko];
    h8 a1 = *(const h8*)&xs[(1 * 16 + cb) * XS1 + ko];
    h8 a2 = *(const h8*)&xs[(2 * 16 + cb) * XS1 + ko];
    h8 a3 = *(const h8*)&xs[(3 * 16 + cb) * XS1 + ko];
    h8 bv = *(const h8*)&bfrag[(((kc << 3) + w) * 64 + l) * 8];
    acc[0] = __builtin_amdgcn_mfma_f32_16x16x32_f16(a0, bv, acc[0], 0, 0, 0);
    acc[1] = __builtin_amdgcn_mfma_f32_16x16x32_f16(a1, bv, acc[1], 0, 0, 0);
    acc[2] = __builtin_amdgcn_mfma_f32_16x16x32_f16(a2, bv, acc[2], 0, 0, 0);
    acc[3] = __builtin_amdgcn_mfma_f32_16x16x32_f16(a3, bv, acc[3], 0, 0, 0);
  }
  __syncthreads();

  for (int t2 = tid; t2 < 64 * 10; t2 += 512) {
    int rl = t2 / 10, j = t2 - rl * 10;
    *(unsigned*)&xs[rl * XS1 + 140 + j * 2] = 0u;
  }
  #pragma unroll
  for (int it = 0; it < 5; it++) {
    int c = tid + it * 512;
    if (c < 64 * 35) {
      int rl = c / 35, kk = (c - rl * 35) * 4;
      int r = rowbase + rl;
      _Float16 o[4] = {0, 0, 0, 0};
      if (r < NN) cvt4(Ain, (size_t)r * DIM + 160 + kk, mode, o);
      _Float16* p = &xs[rl * XS1 + kk];
      p[0] = o[0]; p[1] = o[1]; p[2] = o[2]; p[3] = o[3];
    }
  }
  __syncthreads();
  #pragma unroll
  for (int kc = 5; kc < 10; kc++) {
    int ko = (kc - 5) * 32 + k0base;
    h8 a0 = *(const h8*)&xs[(0 * 16 + cb) * XS1 + ko];
    h8 a1 = *(const h8*)&xs[(1 * 16 + cb) * XS1 + ko];
    h8 a2 = *(const h8*)&xs[(2 * 16 + cb) * XS1 + ko];
    h8 a3 = *(const h8*)&xs[(3 * 16 + cb) * XS1 + ko];
    h8 bv = *(const h8*)&bfrag[(((kc << 3) + w) * 64 + l) * 8];
    acc[0] = __builtin_amdgcn_mfma_f32_16x16x32_f16(a0, bv, acc[0], 0, 0, 0);
    acc[1] = __builtin_amdgcn_mfma_f32_16x16x32_f16(a1, bv, acc[1], 0, 0, 0);
    acc[2] = __builtin_amdgcn_mfma_f32_16x16x32_f16(a2, bv, acc[2], 0, 0, 0);
    acc[3] = __builtin_amdgcn_mfma_f32_16x16x32_f16(a3, bv, acc[3], 0, 0, 0);
  }

  int rquad = (l >> 4) << 2;
  #pragma unroll
  for (int rg = 0; rg < 4; rg++) {
    #pragma unroll
    for (int i = 0; i < 4; i++) {
      int r = rowbase + rg * 16 + rquad + i;
      if (r >= NN) continue;
      float dv = dinv[r];
      outg[(size_t)r * HID + w * 16 + cb] = tohalf(acc[rg][i] * dv);
    }
  }
}

// ============ FUSED agg1 + GEMM2: gather->LDS (gemm2 layout) -> MFMA ============
// block = 64 nodes, 256 thr; 16 agg iterations (4 nodes x 4 waves) then gemm2 phase.

__global__ __launch_bounds__(256)
void k_aggemm2(const __half* __restrict__ g, const float* __restrict__ dinv,
               const int* __restrict__ row_off, const int* __restrict__ csr,
               const float* __restrict__ bias, const _Float16* __restrict__ bfrag,
               __half* __restrict__ outg) {
  __shared__ _Float16 xs[64 * 136];
  int tid = threadIdx.x;
  int w = tid >> 6, l = tid & 63;
  int rowbase = blockIdx.x * 64;
  int grp = l >> 4;
  int cl  = l & 15;
  size_t coff = (size_t)cl * 8;

  // ---- agg phase: 16 iterations, wave w handles node it*4 + w ... wait: 4 waves,
  // node_local = it*4 + w  (w in 0..3) covers 0..63 over it=0..15.
  for (int it = 0; it < 16; it++) {
    int nloc = it * 4 + w;
    int node = rowbase + nloc;
    float a0 = 0.f, a1 = 0.f, a2 = 0.f, a3 = 0.f, a4 = 0.f, a5 = 0.f, a6 = 0.f, a7 = 0.f;
    pack16 r;

    #define ACCUM() do { \
      float2 f0 = __half22float2(r.h2[0]); \
      float2 f1 = __half22float2(r.h2[1]); \
      float2 f2 = __half22float2(r.h2[2]); \
      float2 f3 = __half22float2(r.h2[3]); \
      a0 += f0.x; a1 += f0.y; a2 += f1.x; a3 += f1.y; \
      a4 += f2.x; a5 += f2.y; a6 += f3.x; a7 += f3.y; } while (0)

    int e0 = 0, e1 = 0;
    if (node < NN) { e0 = row_off[node]; e1 = row_off[node + 1]; }
    int e = e0 + grp;
    for (; e + 4 < e1; e += 8) {
      int s1 = csr[e], s2 = csr[e + 4];
      pack16 rA, rB;
      rA.v = *(const float4*)(g + (size_t)s1 * HID + coff);
      rB.v = *(const float4*)(g + (size_t)s2 * HID + coff);
      r = rA; ACCUM();
      r = rB; ACCUM();
    }
    if (e < e1) {
      int s1 = csr[e];
      r.v = *(const float4*)(g + (size_t)s1 * HID + coff);
      ACCUM();
    }
    if (grp == 0 && node < NN) {
      r.v = *(const float4*)(g + (size_t)node * HID + coff);
      ACCUM();
    }
    #undef ACCUM

    a0 += __shfl_xor(a0, 16); a1 += __shfl_xor(a1, 16); a2 += __shfl_xor(a2, 16); a3 += __shfl_xor(a3, 16);
    a4 += __shfl_xor(a4, 16); a5 += __shfl_xor(a5, 16); a6 += __shfl_xor(a6, 16); a7 += __shfl_xor(a7, 16);
    a0 += __shfl_xor(a0, 32); a1 += __shfl_xor(a1, 32); a2 += __shfl_xor(a2, 32); a3 += __shfl_xor(a3, 32);
    a4 += __shfl_xor(a4, 32); a5 += __shfl_xor(a5, 32); a6 += __shfl_xor(a6, 32); a7 += __shfl_xor(a7, 32);

    if (grp == 0) {
      pack16 wv;
      if (node < NN) {
        float di = dinv[node];
        const float* bp = bias + coff;
        wv.h2[0] = __floats2half2_rn(fmaxf(a0 * di + bp[0], 0.f), fmaxf(a1 * di + bp[1], 0.f));
        wv.h2[1] = __floats2half2_rn(fmaxf(a2 * di + bp[2], 0.f), fmaxf(a3 * di + bp[3], 0.f));
        wv.h2[2] = __floats2half2_rn(fmaxf(a4 * di + bp[4], 0.f), fmaxf(a5 * di + bp[5], 0.f));
        wv.h2[3] = __floats2half2_rn(fmaxf(a6 * di + bp[6], 0.f), fmaxf(a7 * di + bp[7], 0.f));
      } else {
        wv.v = make_float4(0.f, 0.f, 0.f, 0.f);
      }
      *(float4*)&xs[nloc * 136 + cl * 8] = wv.v;
    }
  }
  __syncthreads();

  // ---- gemm2 phase (identical to standalone) ----
  int k0base = (l >> 4) << 3;
  int cb = l & 15;
  f4 acc[4][2];
  f4 zero = {0.f, 0.f, 0.f, 0.f};
  #pragma unroll
  for (int rg = 0; rg < 4; rg++) { acc[rg][0] = zero; acc[rg][1] = zero; }

  #pragma unroll
  for (int kc = 0; kc < 4; kc++) {
    int ko = kc * 32 + k0base;
    h8 a0 = *(const h8*)&xs[(0 * 16 + cb) * 136 + ko];
    h8 a1 = *(const h8*)&xs[(1 * 16 + cb) * 136 + ko];
    h8 a2 = *(const h8*)&xs[(2 * 16 + cb) * 136 + ko];
    h8 a3 = *(const h8*)&xs[(3 * 16 + cb) * 136 + ko];
    #pragma unroll
    for (int ntl = 0; ntl < 2; ntl++) {
      int nt = w * 2 + ntl;
      h8 bv = *(const h8*)&bfrag[(((kc << 3) + nt) * 64 + l) * 8];
      acc[0][ntl] = __builtin_amdgcn_mfma_f32_16x16x32_f16(a0, bv, acc[0][ntl], 0, 0, 0);
      acc[1][ntl] = __builtin_amdgcn_mfma_f32_16x16x32_f16(a1, bv, acc[1][ntl], 0, 0, 0);
      acc[2][ntl] = __builtin_amdgcn_mfma_f32_16x16x32_f16(a2, bv, acc[2][ntl], 0, 0, 0);
      acc[3][ntl] = __builtin_amdgcn_mfma_f32_16x16x32_f16(a3, bv, acc[3][ntl], 0, 0, 0);
    }
  }

  int rquad = (l >> 4) << 2;
  #pragma unroll
  for (int rg = 0; rg < 4; rg++) {
    #pragma unroll
    for (int i = 0; i < 4; i++) {
      int r = rowbase + rg * 16 + rquad + i;
      if (r >= NN) continue;
      float dv = dinv[r];
      __half* orow = outg + (size_t)r * HID;
      orow[(w * 2 + 0) * 16 + cb] = tohalf(acc[rg][0][i] * dv);
      orow[(w * 2 + 1) * 16 + cb] = tohalf(acc[rg][1][i] * dv);
    }
  }
}

// ------- aggregation (layer 2): 4 edges in flight per wave, 16B/lane gathers -------

__global__ __launch_bounds__(256)
void k_agg(const __half* __restrict__ g, const float* __restrict__ dinv,
           const int* __restrict__ row_off, const int* __restrict__ csr,
           const float* __restrict__ bias, __half* __restrict__ out) {
  int tid = threadIdx.x;
  int node = blockIdx.x * 4 + (tid >> 6);
  int l = tid & 63;
  if (node >= NN) return;
  int grp = l >> 4;
  int cl  = l & 15;
  size_t coff = (size_t)cl * 8;

  float a0 = 0.f, a1 = 0.f, a2 = 0.f, a3 = 0.f, a4 = 0.f, a5 = 0.f, a6 = 0.f, a7 = 0.f;
  pack16 r;

  #define ACCUM() do { \
    float2 f0 = __half22float2(r.h2[0]); \
    float2 f1 = __half22float2(r.h2[1]); \
    float2 f2 = __half22float2(r.h2[2]); \
    float2 f3 = __half22float2(r.h2[3]); \
    a0 += f0.x; a1 += f0.y; a2 += f1.x; a3 += f1.y; \
    a4 += f2.x; a5 += f2.y; a6 += f3.x; a7 += f3.y; } while (0)

  int e0 = row_off[node], e1 = row_off[node + 1];
  int e = e0 + grp;
  for (; e + 4 < e1; e += 8) {
    int s1 = csr[e], s2 = csr[e + 4];
    pack16 rA, rB;
    rA.v = *(const float4*)(g + (size_t)s1 * HID + coff);
    rB.v = *(const float4*)(g + (size_t)s2 * HID + coff);
    r = rA; ACCUM();
    r = rB; ACCUM();
  }
  if (e < e1) {
    int s1 = csr[e];
    r.v = *(const float4*)(g + (size_t)s1 * HID + coff);
    ACCUM();
  }
  if (grp == 0) {
    r.v = *(const float4*)(g + (size_t)node * HID + coff);
    ACCUM();
  }
  #undef ACCUM

  a0 += __shfl_xor(a0, 16); a1 += __shfl_xor(a1, 16); a2 += __shfl_xor(a2, 16); a3 += __shfl_xor(a3, 16);
  a4 += __shfl_xor(a4, 16); a5 += __shfl_xor(a5, 16); a6 += __shfl_xor(a6, 16); a7 += __shfl_xor(a7, 16);
  a0 += __shfl_xor(a0, 32); a1 += __shfl_xor(a1, 32); a2 += __shfl_xor(a2, 32); a3 += __shfl_xor(a3, 32);
  a4 += __shfl_xor(a4, 32); a5 += __shfl_xor(a5, 32); a6 += __shfl_xor(a6, 32); a7 += __shfl_xor(a7, 32);

  if (grp == 0) {
    float di = dinv[node];
    const float* bp = bias + coff;
    pack16 w;
    w.h2[0] = __floats2half2_rn(fmaxf(a0 * di + bp[0], 0.f), fmaxf(a1 * di + bp[1], 0.f));
    w.h2[1] = __floats2half2_rn(fmaxf(a2 * di + bp[2], 0.f), fmaxf(a3 * di + bp[3], 0.f));
    w.h2[2] = __floats2half2_rn(fmaxf(a4 * di + bp[4], 0.f), fmaxf(a5 * di + bp[5], 0.f));
    w.h2[3] = __floats2half2_rn(fmaxf(a6 * di + bp[6], 0.f), fmaxf(a7 * di + bp[7], 0.f));
    *(float4*)(out + (size_t)node * HID + coff) = w.v;
  }
}

// ------- pooling + head fused: one graph per 256-thr block -------

__global__ __launch_bounds__(256)
void k_pool(const __half* __restrict__ o2, const void* __restrict__ Araw, const void* __restrict__ Braw,
            const int* __restrict__ gstart, const int* __restrict__ flags,
            const float* __restrict__ Wout, const float* __restrict__ bout,
            float* __restrict__ out) {
  __shared__ float lex[4][HID];
  __shared__ float lnx[4][HID];
  __shared__ int lec[4];
  __shared__ float ldoc[HID];
  int gid = blockIdx.x, tid = threadIdx.x;
  int wv = tid >> 6, l = tid & 63;
  int grp = l >> 4, cl = l & 15;
  size_t coff = (size_t)cl * 8;
  const int mint = flags[1];
  const void* mraw = flags[2] ? Araw : Braw;
  const unsigned char* m8 = (const unsigned char*)mraw;
  const int* m32 = (const int*)mraw;
  int s = gstart[gid], e = gstart[gid + 1];

  float ex[8], nx[8];
  #pragma unroll
  for (int j = 0; j < 8; j++) { ex[j] = 0.f; nx[j] = 0.f; }
  int ec = 0;

  for (int n = s + wv * 4 + grp; n < e; n += 16) {
    pack16 r;
    r.v = *(const float4*)(o2 + (size_t)n * HID + coff);
    float2 f0 = __half22float2(r.h2[0]);
    float2 f1 = __half22float2(r.h2[1]);
    float2 f2 = __half22float2(r.h2[2]);
    float2 f3 = __half22float2(r.h2[3]);
    float t0 = f0.x, t1 = f0.y, t2 = f1.x, t3 = f1.y;
    float t4 = f2.x, t5 = f2.y, t6 = f3.x, t7 = f3.y;
    nx[0] += t0; nx[1] += t1; nx[2] += t2; nx[3] += t3;
    nx[4] += t4; nx[5] += t5; nx[6] += t6; nx[7] += t7;
    bool mv = mint ? (m32[n] != 0) : (m8[n] != 0);
    if (mv) {
      ex[0] += t0; ex[1] += t1; ex[2] += t2; ex[3] += t3;
      ex[4] += t4; ex[5] += t5; ex[6] += t6; ex[7] += t7;
      ec++;
    }
  }
  #pragma unroll
  for (int j = 0; j < 8; j++) {
    ex[j] += __shfl_xor(ex[j], 16); ex[j] += __shfl_xor(ex[j], 32);
    nx[j] += __shfl_xor(nx[j], 16); nx[j] += __shfl_xor(nx[j], 32);
  }
  ec += __shfl_xor(ec, 16); ec += __shfl_xor(ec, 32);

  if (grp == 0) {
    #pragma unroll
    for (int j = 0; j < 8; j++) { lex[wv][cl * 8 + j] = ex[j]; lnx[wv][cl * 8 + j] = nx[j]; }
    if (cl == 0) lec[wv] = ec;
  }
  __syncthreads();
  if (tid < HID) {
    float exT = lex[0][tid] + lex[1][tid] + lex[2][tid] + lex[3][tid];
    float nxT = lnx[0][tid] + lnx[1][tid] + lnx[2][tid] + lnx[3][tid];
    int ecT = lec[0] + lec[1] + lec[2] + lec[3];
    int cnt = e - s;
    float dv;
    if (ecT > 0) dv = exT / ((float)ecT + 1e-6f);
    else dv = (cnt > 0) ? nxT / (float)cnt : 0.f;
    ldoc[tid] = dv;
  }
  __syncthreads();
  if (tid < 64) {
    float logit = -1e30f;
    if (tid < NC) {
      float acc = bout[tid];
      for (int k = 0; k < HID; k++) acc += ldoc[k] * Wout[k * NC + tid];
      logit = acc;
    }
    float m = logit;
    for (int off = 32; off; off >>= 1) m = fmaxf(m, __shfl_xor(m, off));
    float exv = (tid < NC) ? expf(logit - m) : 0.f;
    float ssum = exv;
    for (int off = 32; off; off >>= 1) ssum += __shfl_xor(ssum, off);
    if (tid < NC) out[gid * NC + tid] = (logit - m) - logf(ssum);
  }
}

__global__ void k_fail(float* __restrict__ out, float enc) {
  int i = blockIdx.x * blockDim.x + threadIdx.x;
  if (i < NG * NC) out[i] = -enc;
}

// ================= launch =================

extern "C" void kernel_launch(void* const* d_in, const int* in_sizes, int n_in,
                              void* d_out, int out_size, void* d_ws, size_t ws_size,
                              hipStream_t stream) {
  int ix = -1, iei = -1, iA = -1, iB = -1, iW1 = -1, ib1 = -1, iW2 = -1, ib2 = -1, iWo = -1, ibo = -1;
  for (int i = 0; i < n_in; i++) {
    int s = in_sizes[i];
    if (s == 30000000) ix = i;
    else if (s == 3200000) iei = i;
    else if (s == 100000) { if (iA < 0) iA = i; else iB = i; }
    else if (s == 38400) iW1 = i;
    else if (s == 16384) iW2 = i;
    else if (s == 2560) iWo = i;
    else if (s == 20) ibo = i;
    else if (s == 128) { if (ib1 < 0) ib1 = i; else ib2 = i; }
  }
  float* out = (float*)d_out;
  int miss = -1;
  if (ix < 0) miss = 0; else if (iei < 0) miss = 1; else if (iA < 0 || iB < 0) miss = 2;
  else if (iW1 < 0) miss = 3; else if (ib1 < 0 || ib2 < 0) miss = 4; else if (iW2 < 0) miss = 5;
  else if (iWo < 0) miss = 6; else if (ibo < 0) miss = 7;
  if (miss >= 0) {
    k_fail<<<(NG * NC + 255) / 256, 256, 0, stream>>>(out, 8192.f + 64.f * (float)miss);
    return;
  }
  const void* x = d_in[ix];
  const int* e32 = (const int*)d_in[iei];
  const void* Araw = d_in[iA];
  const void* Braw = d_in[iB];
  const float* W1 = (const float*)d_in[iW1];
  const float* b1 = (const float*)d_in[ib1];
  const float* W2 = (const float*)d_in[iW2];
  const float* b2 = (const float*)d_in[ib2];
  const float* Wout = (const float*)d_in[iWo];
  const float* bout = (const float*)d_in[ibo];

  char* ws = (char*)d_ws;
  size_t off = 0;
  auto alloc = [&](size_t bytes) -> char* {
    char* p = ws + off; off += (bytes + 255) & ~(size_t)255; return p;
  };
  float* dinv   = (float*)alloc((size_t)NN * 4);
  int* row_off  = (int*)alloc((size_t)(NN + 1) * 4);
  int* csr      = (int*)alloc((size_t)NE * 4);
  int* bcnt     = (int*)alloc((size_t)NBK * 4);
  int* boff     = (int*)alloc((size_t)(NBK + 1) * 4);
  int* bcur     = (int*)alloc((size_t)NBK * 4);
  int* gstart   = (int*)alloc((size_t)(NG + 1) * 4);
  int* flags    = (int*)alloc(8 * 4);
  _Float16* w1f = (_Float16*)alloc(40960 * 2);
  _Float16* w2f = (_Float16*)alloc(16384 * 2);
  __half* gbuf  = (__half*)alloc((size_t)NN * HID * 2);
  __half* obuf  = (__half*)alloc((size_t)NN * HID * 2);
  unsigned* diag = (unsigned*)alloc(64 * 4);
  unsigned* ebuf = (unsigned*)gbuf;   // overlay: dead before gemm1 writes gbuf

  hipMemsetAsync(diag, 0, 64 * 4, stream);

  k_probe<<<326, 256, 0, stream>>>((const unsigned short*)x, (const unsigned*)Araw,
                                   (const unsigned*)Braw, e32, W1, W2, w1f, w2f, diag);
  k_setup<<<1, 576, 0, stream>>>(diag, flags, (const int*)Araw, (const int*)Braw, bcnt, gstart);

  k_bhist<<<1024, 256, 0, stream>>>(e32, flags, bcnt, boff, bcur, &diag[32]);
  k_bscatter<<<(NE + BCH - 1) / BCH, 256, 0, stream>>>(e32, flags, bcur, ebuf);
  k_bfinal<<<NBK, 256, 0, stream>>>(ebuf, boff, row_off, dinv, csr);

  // network
  k_gemm1_mfma<<<(NN + 63) / 64, 512, 0, stream>>>(x, w1f, dinv, flags, gbuf);
  k_aggemm2<<<(NN + 63) / 64, 256, 0, stream>>>(gbuf, dinv, row_off, csr, b1, w2f, obuf);
  k_agg<<<NN / 4, 256, 0, stream>>>(obuf, dinv, row_off, csr, b2, gbuf);

  k_pool<<<NG, 256, 0, stream>>>(gbuf, Araw, Braw, gstart, flags, Wout, bout, out);
}

// Round 26
// 344.767 us; speedup vs baseline: 1.1008x; 1.1008x over previous
//
#include <hip/hip_runtime.h>
#include <hip/hip_fp16.h>

#define NN 100000
#define NE 1600000
#define DIM 300
#define HID 128
#define NC 20
#define NG 512
#define NBK 196        // buckets of 512 nodes
#define BCH 4096       // edges per scatter chunk

typedef _Float16 h8 __attribute__((ext_vector_type(8)));
typedef float f4 __attribute__((ext_vector_type(4)));

union pack16 { float4 v; __half2 h2[4]; };

__device__ __forceinline__ __half tohalf(float v) {
  if (!(v == v)) v = 0.f;
  v = fminf(fmaxf(v, -60000.f), 60000.f);
  return __float2half(v);
}

__device__ __forceinline__ float load_x(const void* xraw, size_t o, int mode) {
  float v;
  if (mode == 2) v = ((const float*)xraw)[o];
  else {
    unsigned short u = ((const unsigned short*)xraw)[o];
    if (mode == 1) { union { unsigned w; float f; } c; c.w = ((unsigned)u) << 16; v = c.f; }
    else { union { unsigned short s; _Float16 h; } c; c.s = u; v = (float)c.h; }
  }
  if (!(v == v)) v = 0.f;
  return fminf(fmaxf(v, -1e4f), 1e4f);
}

__device__ __forceinline__ void cvt4(const void* Ain, size_t off, int mode, _Float16* o) {
  if (mode == 2) {
    float4 fv = *(const float4*)((const float*)Ain + off);
    o[0] = (_Float16)fv.x; o[1] = (_Float16)fv.y; o[2] = (_Float16)fv.z; o[3] = (_Float16)fv.w;
  } else {
    uint2 u = *(const uint2*)((const unsigned short*)Ain + off);
    unsigned short s0 = u.x & 0xFFFF, s1 = u.x >> 16, s2 = u.y & 0xFFFF, s3 = u.y >> 16;
    if (mode == 1) {
      union { unsigned w; float f; } c0, c1, c2, c3;
      c0.w = ((unsigned)s0) << 16; c1.w = ((unsigned)s1) << 16;
      c2.w = ((unsigned)s2) << 16; c3.w = ((unsigned)s3) << 16;
      o[0] = (_Float16)c0.f; o[1] = (_Float16)c1.f; o[2] = (_Float16)c2.f; o[3] = (_Float16)c3.f;
    } else {
      union { unsigned short s; _Float16 h; } d0, d1, d2, d3;
      d0.s = s0; d1.s = s1; d2.s = s2; d3.s = s3;
      o[0] = d0.h; o[1] = d1.h; o[2] = d2.h; o[3] = d3.h;
    }
  }
}

// ============ merged probe + weight-prep kernel ============

__global__ void k_probe(const unsigned short* __restrict__ xu,
                        const unsigned* __restrict__ Araw, const unsigned* __restrict__ Braw,
                        const int* __restrict__ e32,
                        const float* __restrict__ W1, const float* __restrict__ W2,
                        _Float16* __restrict__ w1f, _Float16* __restrict__ w2f,
                        unsigned* __restrict__ diag) {
  int b = blockIdx.x, t = threadIdx.x;
  if (b < 96) {
    int mode = b % 3, chunk = b / 3;
    float m = 0.f;
    if (mode == 0) {
      int base = chunk * 16384;
      for (int j = t; j < 16384; j += 256) {
        union { unsigned short s; _Float16 h; } c; c.s = xu[base + j];
        float v = fabsf((float)c.h);
        if (v == v && v < 65000.f) m = fmaxf(m, v);
      }
    } else if (mode == 1) {
      int base = chunk * 16384;
      for (int j = t; j < 16384; j += 256) {
        union { unsigned w; float f; } c; c.w = ((unsigned)xu[base + j]) << 16;
        float v = fabsf(c.f);
        if (v == v && v < 1e30f) m = fmaxf(m, v);
      }
    } else {
      const float* xf = (const float*)xu;
      int base = chunk * 8192;
      for (int j = t; j < 8192; j += 256) {
        float v = fabsf(xf[base + j]);
        if (v == v && v < 1e30f) m = fmaxf(m, v);
      }
    }
    for (int off = 32; off; off >>= 1) m = fmaxf(m, __shfl_xor(m, off));
    if ((t & 63) == 0) atomicMax(&diag[20 + mode], __float_as_uint(m));
  } else if (b == 96 || b == 97) {
    __shared__ unsigned red[256];
    const unsigned* p = (b == 96) ? Araw : Braw;
    unsigned m = 0;
    for (int j = t; j < 25000; j += 256) m = max(m, p[j]);
    red[t] = m; __syncthreads();
    for (int off = 128; off; off >>= 1) { if (t < off) red[t] = max(red[t], red[t + off]); __syncthreads(); }
    if (t == 0) diag[(b == 96) ? 24 : 25] = red[0];
  } else if (b < 102) {
    int i = (b - 98) * 256 + t;
    unsigned z = 0;
    for (; i < 50000; i += 1024) if (e32[2 * i + 1] == 0) z++;
    for (int off = 32; off; off >>= 1) z += __shfl_xor(z, off);
    if ((t & 63) == 0) atomicAdd(&diag[26], z);
  } else {
    int idx = (b - 102) * 256 + t;
    const int S1 = 10 * 8 * 64 * 8;  // 40960
    const int S2 = 4 * 8 * 64 * 8;   // 16384
    if (idx < S1) {
      int j = idx & 7, l = (idx >> 3) & 63, nt = (idx >> 9) & 7, kc = idx >> 12;
      int k = kc * 32 + ((l >> 4) << 3) + j;
      int n = nt * 16 + (l & 15);
      w1f[idx] = (k < DIM) ? (_Float16)W1[k * HID + n] : (_Float16)0.f;
    } else if (idx < S1 + S2) {
      int q = idx - S1;
      int j = q & 7, l = (q >> 3) & 63, nt = (q >> 9) & 7, kc = q >> 12;
      int k = kc * 32 + ((l >> 4) << 3) + j;
      int n = nt * 16 + (l & 15);
      w2f[q] = (_Float16)W2[k * HID + n];
    }
  }
}

// ============ merged setup: decide flags + gstart + bcnt zero ============

__global__ void k_setup(const unsigned* __restrict__ diag, int* __restrict__ flags,
                        const int* __restrict__ A, const int* __restrict__ B,
                        int* __restrict__ bcnt, int* __restrict__ gstart) {
  __shared__ int sflags[8];
  int t = threadIdx.x;
  if (t == 0) {
    float M16 = __uint_as_float(diag[20]);
    float M32 = __uint_as_float(diag[21]);
    float Mf  = __uint_as_float(diag[22]);
    int xmode = 3;
    if      (Mf  > 3.f && Mf  < 8.f) xmode = 2;
    else if (M32 > 3.f && M32 < 8.f) xmode = 1;
    else if (M16 > 3.f && M16 < 8.f) xmode = 0;
    unsigned uA = diag[24], uB = diag[25];
    bool Ab = (uA >= 32u && uA < 1024u), Bb = (uB >= 32u && uB < 1024u);
    int swap = -1;
    if (Ab && !Bb) swap = 0;
    else if (Bb && !Ab) swap = 1;
    int mint = -1;
    if (swap >= 0) {
      unsigned um = (swap == 0) ? uB : uA;
      if (um <= 1u) mint = 1;
      else if (um >= 65536u) mint = 0;
    }
    sflags[0] = xmode;
    sflags[1] = (mint == 1) ? 1 : 0;
    sflags[2] = (swap == 1) ? 1 : 0;
    sflags[3] = (diag[26] >= 49990u) ? 1 : 0;
    sflags[4] = (swap >= 0 && mint >= 0) ? 1 : 0;
    #pragma unroll
    for (int j = 0; j < 5; j++) flags[j] = sflags[j];
  }
  __syncthreads();
  const int* batch = sflags[2] ? B : A;
  if (t <= NG) {
    if (t == NG) gstart[NG] = NN;
    else {
      int lo = 0, hi = NN;
      while (lo < hi) { int mid = (lo + hi) >> 1; if (batch[mid] < t) lo = mid + 1; else hi = mid; }
      gstart[t] = lo;
    }
  }
  if (t < NBK) bcnt[t] = 0;
}

// ================= bucketed CSR build (hist + last-block scan) =================

__global__ void k_bhist(const int* __restrict__ e32, const int* __restrict__ flags,
                        int* __restrict__ bcnt, int* __restrict__ boff,
                        int* __restrict__ bcur, unsigned* __restrict__ done) {
  __shared__ int hist[NBK];
  int e64 = flags[3];
  int t = threadIdx.x;
  for (int j = t; j < NBK; j += 256) hist[j] = 0;
  __syncthreads();
  int i = blockIdx.x * blockDim.x + t;
  int stride = gridDim.x * blockDim.x;
  for (; i < NE; i += stride) {
    int s = e64 ? e32[2 * i] : e32[i];
    int d = e64 ? e32[2 * NE + 2 * i] : e32[NE + i];
    if ((unsigned)s < (unsigned)NN && (unsigned)d < (unsigned)NN)
      atomicAdd(&hist[d >> 9], 1);
  }
  __syncthreads();
  for (int j = t; j < NBK; j += 256) if (hist[j]) atomicAdd(&bcnt[j], hist[j]);
  __threadfence();
  __syncthreads();
  if (t == 0) {
    if (atomicAdd(done, 1u) == gridDim.x - 1) {
      int run = 0;
      for (int j = 0; j < NBK; j++) { boff[j] = run; bcur[j] = run; run += bcnt[j]; }
      boff[NBK] = run;
    }
  }
}

__global__ __launch_bounds__(256)
void k_bscatter(const int* __restrict__ e32, const int* __restrict__ flags,
                int* __restrict__ bcur, unsigned* __restrict__ ebuf) {
  __shared__ uint2 stage[BCH];           // 32 KB
  __shared__ int hist[NBK];
  __shared__ int lbase[NBK];
  __shared__ int lcur[NBK];
  int e64 = flags[3];
  int t = threadIdx.x;
  for (int j = t; j < NBK; j += 256) { hist[j] = 0; lcur[j] = 0; }
  __syncthreads();
  int start = blockIdx.x * BCH;
  int n = NE - start; if (n > BCH) n = BCH;
  for (int i = t; i < n; i += 256) {
    int idx = start + i;
    int s = e64 ? e32[2 * idx] : e32[idx];
    int d = e64 ? e32[2 * NE + 2 * idx] : e32[NE + idx];
    bool ok = ((unsigned)s < (unsigned)NN) && ((unsigned)d < (unsigned)NN);
    stage[i] = make_uint2(ok ? (unsigned)s : 0xFFFFFFFFu, (unsigned)(ok ? d : 0));
    if (ok) atomicAdd(&hist[d >> 9], 1);
  }
  __syncthreads();
  for (int j = t; j < NBK; j += 256) if (hist[j] > 0) lbase[j] = atomicAdd(&bcur[j], hist[j]);
  __syncthreads();
  for (int i = t; i < n; i += 256) {
    unsigned s = stage[i].x;
    if (s == 0xFFFFFFFFu) continue;
    int d = (int)stage[i].y;
    int b = d >> 9;
    int o = atomicAdd(&lcur[b], 1);
    ebuf[lbase[b] + o] = (s << 9) | (unsigned)(d & 511);
  }
}

__global__ __launch_bounds__(256)
void k_bfinal(const unsigned* __restrict__ ebuf, const int* __restrict__ boff,
              int* __restrict__ row_off, float* __restrict__ dinv, int* __restrict__ csr) {
  __shared__ int ldeg[512];
  __shared__ int lcur[512];
  int b = blockIdx.x, t = threadIdx.x;
  int base = b * 512;
  int nn = NN - base; if (nn > 512) nn = 512;
  for (int j = t; j < 512; j += 256) ldeg[j] = 0;
  __syncthreads();
  int s0 = boff[b], s1 = boff[b + 1];
  for (int e = s0 + t; e < s1; e += 256) atomicAdd(&ldeg[ebuf[e] & 511], 1);
  __syncthreads();
  if (t == 0) {
    int run = s0;
    for (int i = 0; i < nn; i++) { lcur[i] = run; row_off[base + i] = run; run += ldeg[i]; }
    if (b == gridDim.x - 1) row_off[NN] = run;
  }
  __syncthreads();
  for (int j = t; j < nn; j += 256) dinv[base + j] = rsqrtf((float)ldeg[j] + 1.0f);
  for (int e = s0 + t; e < s1; e += 256) {
    unsigned v = ebuf[e];
    int p = atomicAdd(&lcur[v & 511], 1);
    csr[p] = (int)(v >> 9);
  }
}

// ============ GEMM1: 512-thread blocks (8 waves, 1 nt each), two-pass K-split ============

#define XS1 168

__global__ __launch_bounds__(512)
void k_gemm1_mfma(const void* __restrict__ Ain, const _Float16* __restrict__ bfrag,
                  const float* __restrict__ dinv, const int* __restrict__ flags,
                  __half* __restrict__ outg) {
  __shared__ _Float16 xs[64 * XS1];   // 21504 B
  const int mode = flags[0] & 3;
  int tid = threadIdx.x;
  int w = tid >> 6, l = tid & 63;
  int rowbase = blockIdx.x * 64;
  int k0base = (l >> 4) << 3;
  int cb = l & 15;

  f4 acc[4];
  f4 zero = {0.f, 0.f, 0.f, 0.f};
  #pragma unroll
  for (int rg = 0; rg < 4; rg++) acc[rg] = zero;

  #pragma unroll
  for (int it = 0; it < 5; it++) {
    int c = tid + it * 512;
    int rl = c / 40, kk = (c - rl * 40) * 4;
    int r = rowbase + rl;
    _Float16 o[4] = {0, 0, 0, 0};
    if (r < NN) cvt4(Ain, (size_t)r * DIM + kk, mode, o);
    _Float16* p = &xs[rl * XS1 + kk];
    p[0] = o[0]; p[1] = o[1]; p[2] = o[2]; p[3] = o[3];
  }
  __syncthreads();
  #pragma unroll
  for (int kc = 0; kc < 5; kc++) {
    int ko = kc * 32 + k0base;
    h8 a0 = *(const h8*)&xs[(0 * 16 + cb) * XS1 + ko];
    h8 a1 = *(const h8*)&xs[(1 * 16 + cb) * XS1 + ko];
    h8 a2 = *(const h8*)&xs[(2 * 16 + cb) * XS1 + ko];
    h8 a3 = *(const h8*)&xs[(3 * 16 + cb) * XS1 + ko];
    h8 bv = *(const h8*)&bfrag[(((kc << 3) + w) * 64 + l) * 8];
    acc[0] = __builtin_amdgcn_mfma_f32_16x16x32_f16(a0, bv, acc[0], 0, 0, 0);
    acc[1] = __builtin_amdgcn_mfma_f32_16x16x32_f16(a1, bv, acc[1], 0, 0, 0);
    acc[2] = __builtin_amdgcn_mfma_f32_16x16x32_f16(a2, bv, acc[2], 0, 0, 0);
    acc[3] = __builtin_amdgcn_mfma_f32_16x16x32_f16(a3, bv, acc[3], 0, 0, 0);
  }
  __syncthreads();

  for (int t2 = tid; t2 < 64 * 10; t2 += 512) {
    int rl = t2 / 10, j = t2 - rl * 10;
    *(unsigned*)&xs[rl * XS1 + 140 + j * 2] = 0u;
  }
  #pragma unroll
  for (int it = 0; it < 5; it++) {
    int c = tid + it * 512;
    if (c < 64 * 35) {
      int rl = c / 35, kk = (c - rl * 35) * 4;
      int r = rowbase + rl;
      _Float16 o[4] = {0, 0, 0, 0};
      if (r < NN) cvt4(Ain, (size_t)r * DIM + 160 + kk, mode, o);
      _Float16* p = &xs[rl * XS1 + kk];
      p[0] = o[0]; p[1] = o[1]; p[2] = o[2]; p[3] = o[3];
    }
  }
  __syncthreads();
  #pragma unroll
  for (int kc = 5; kc < 10; kc++) {
    int ko = (kc - 5) * 32 + k0base;
    h8 a0 = *(const h8*)&xs[(0 * 16 + cb) * XS1 + ko];
    h8 a1 = *(const h8*)&xs[(1 * 16 + cb) * XS1 + ko];
    h8 a2 = *(const h8*)&xs[(2 * 16 + cb) * XS1 + ko];
    h8 a3 = *(const h8*)&xs[(3 * 16 + cb) * XS1 + ko];
    h8 bv = *(const h8*)&bfrag[(((kc << 3) + w) * 64 + l) * 8];
    acc[0] = __builtin_amdgcn_mfma_f32_16x16x32_f16(a0, bv, acc[0], 0, 0, 0);
    acc[1] = __builtin_amdgcn_mfma_f32_16x16x32_f16(a1, bv, acc[1], 0, 0, 0);
    acc[2] = __builtin_amdgcn_mfma_f32_16x16x32_f16(a2, bv, acc[2], 0, 0, 0);
    acc[3] = __builtin_amdgcn_mfma_f32_16x16x32_f16(a3, bv, acc[3], 0, 0, 0);
  }

  int rquad = (l >> 4) << 2;
  #pragma unroll
  for (int rg = 0; rg < 4; rg++) {
    #pragma unroll
    for (int i = 0; i < 4; i++) {
      int r = rowbase + rg * 16 + rquad + i;
      if (r >= NN) continue;
      float dv = dinv[r];
      outg[(size_t)r * HID + w * 16 + cb] = tohalf(acc[rg][i] * dv);
    }
  }
}

// ============ GEMM2: batched staging + nt-pair waves ============

__global__ __launch_bounds__(256)
void k_gemm2_mfma(const __half* __restrict__ Ain, const _Float16* __restrict__ bfrag,
                  const float* __restrict__ dinv, __half* __restrict__ outg) {
  __shared__ _Float16 xs[64 * 136];
  int tid = threadIdx.x;
  int w = tid >> 6, l = tid & 63;
  int rowbase = blockIdx.x * 64;
  int k0base = (l >> 4) << 3;
  int cb = l & 15;

  {
    h8 regs[4];
    #pragma unroll
    for (int it = 0; it < 4; it++) {
      int c = tid + it * 256;
      int rl = c >> 4, k = (c & 15) * 8;
      int r = rowbase + rl;
      h8 v = {};
      if (r < NN) v = *(const h8*)((const _Float16*)Ain + (size_t)r * HID + k);
      regs[it] = v;
    }
    __builtin_amdgcn_sched_barrier(0);
    #pragma unroll
    for (int it = 0; it < 4; it++) {
      int c = tid + it * 256;
      int rl = c >> 4, k = (c & 15) * 8;
      *(h8*)&xs[rl * 136 + k] = regs[it];
    }
  }
  __syncthreads();

  f4 acc[4][2];
  f4 zero = {0.f, 0.f, 0.f, 0.f};
  #pragma unroll
  for (int rg = 0; rg < 4; rg++) { acc[rg][0] = zero; acc[rg][1] = zero; }

  #pragma unroll
  for (int kc = 0; kc < 4; kc++) {
    int ko = kc * 32 + k0base;
    h8 a0 = *(const h8*)&xs[(0 * 16 + cb) * 136 + ko];
    h8 a1 = *(const h8*)&xs[(1 * 16 + cb) * 136 + ko];
    h8 a2 = *(const h8*)&xs[(2 * 16 + cb) * 136 + ko];
    h8 a3 = *(const h8*)&xs[(3 * 16 + cb) * 136 + ko];
    #pragma unroll
    for (int ntl = 0; ntl < 2; ntl++) {
      int nt = w * 2 + ntl;
      h8 bv = *(const h8*)&bfrag[(((kc << 3) + nt) * 64 + l) * 8];
      acc[0][ntl] = __builtin_amdgcn_mfma_f32_16x16x32_f16(a0, bv, acc[0][ntl], 0, 0, 0);
      acc[1][ntl] = __builtin_amdgcn_mfma_f32_16x16x32_f16(a1, bv, acc[1][ntl], 0, 0, 0);
      acc[2][ntl] = __builtin_amdgcn_mfma_f32_16x16x32_f16(a2, bv, acc[2][ntl], 0, 0, 0);
      acc[3][ntl] = __builtin_amdgcn_mfma_f32_16x16x32_f16(a3, bv, acc[3][ntl], 0, 0, 0);
    }
  }

  int rquad = (l >> 4) << 2;
  #pragma unroll
  for (int rg = 0; rg < 4; rg++) {
    #pragma unroll
    for (int i = 0; i < 4; i++) {
      int r = rowbase + rg * 16 + rquad + i;
      if (r >= NN) continue;
      float dv = dinv[r];
      __half* orow = outg + (size_t)r * HID;
      orow[(w * 2 + 0) * 16 + cb] = tohalf(acc[rg][0][i] * dv);
      orow[(w * 2 + 1) * 16 + cb] = tohalf(acc[rg][1][i] * dv);
    }
  }
}

// ------- aggregation: 4 edges in flight per wave, 16B/lane gathers -------

__global__ __launch_bounds__(256)
void k_agg(const __half* __restrict__ g, const float* __restrict__ dinv,
           const int* __restrict__ row_off, const int* __restrict__ csr,
           const float* __restrict__ bias, __half* __restrict__ out) {
  int tid = threadIdx.x;
  int node = blockIdx.x * 4 + (tid >> 6);
  int l = tid & 63;
  if (node >= NN) return;
  int grp = l >> 4;
  int cl  = l & 15;
  size_t coff = (size_t)cl * 8;

  float a0 = 0.f, a1 = 0.f, a2 = 0.f, a3 = 0.f, a4 = 0.f, a5 = 0.f, a6 = 0.f, a7 = 0.f;
  pack16 r;

  #define ACCUM() do { \
    float2 f0 = __half22float2(r.h2[0]); \
    float2 f1 = __half22float2(r.h2[1]); \
    float2 f2 = __half22float2(r.h2[2]); \
    float2 f3 = __half22float2(r.h2[3]); \
    a0 += f0.x; a1 += f0.y; a2 += f1.x; a3 += f1.y; \
    a4 += f2.x; a5 += f2.y; a6 += f3.x; a7 += f3.y; } while (0)

  int e0 = row_off[node], e1 = row_off[node + 1];
  int e = e0 + grp;
  for (; e + 4 < e1; e += 8) {
    int s1 = csr[e], s2 = csr[e + 4];
    pack16 rA, rB;
    rA.v = *(const float4*)(g + (size_t)s1 * HID + coff);
    rB.v = *(const float4*)(g + (size_t)s2 * HID + coff);
    r = rA; ACCUM();
    r = rB; ACCUM();
  }
  if (e < e1) {
    int s1 = csr[e];
    r.v = *(const float4*)(g + (size_t)s1 * HID + coff);
    ACCUM();
  }
  if (grp == 0) {
    r.v = *(const float4*)(g + (size_t)node * HID + coff);
    ACCUM();
  }
  #undef ACCUM

  a0 += __shfl_xor(a0, 16); a1 += __shfl_xor(a1, 16); a2 += __shfl_xor(a2, 16); a3 += __shfl_xor(a3, 16);
  a4 += __shfl_xor(a4, 16); a5 += __shfl_xor(a5, 16); a6 += __shfl_xor(a6, 16); a7 += __shfl_xor(a7, 16);
  a0 += __shfl_xor(a0, 32); a1 += __shfl_xor(a1, 32); a2 += __shfl_xor(a2, 32); a3 += __shfl_xor(a3, 32);
  a4 += __shfl_xor(a4, 32); a5 += __shfl_xor(a5, 32); a6 += __shfl_xor(a6, 32); a7 += __shfl_xor(a7, 32);

  if (grp == 0) {
    float di = dinv[node];
    const float* bp = bias + coff;
    pack16 w;
    w.h2[0] = __floats2half2_rn(fmaxf(a0 * di + bp[0], 0.f), fmaxf(a1 * di + bp[1], 0.f));
    w.h2[1] = __floats2half2_rn(fmaxf(a2 * di + bp[2], 0.f), fmaxf(a3 * di + bp[3], 0.f));
    w.h2[2] = __floats2half2_rn(fmaxf(a4 * di + bp[4], 0.f), fmaxf(a5 * di + bp[5], 0.f));
    w.h2[3] = __floats2half2_rn(fmaxf(a6 * di + bp[6], 0.f), fmaxf(a7 * di + bp[7], 0.f));
    *(float4*)(out + (size_t)node * HID + coff) = w.v;
  }
}

// ------- pooling + head fused: one graph per 256-thr block -------

__global__ __launch_bounds__(256)
void k_pool(const __half* __restrict__ o2, const void* __restrict__ Araw, const void* __restrict__ Braw,
            const int* __restrict__ gstart, const int* __restrict__ flags,
            const float* __restrict__ Wout, const float* __restrict__ bout,
            float* __restrict__ out) {
  __shared__ float lex[4][HID];
  __shared__ float lnx[4][HID];
  __shared__ int lec[4];
  __shared__ float ldoc[HID];
  int gid = blockIdx.x, tid = threadIdx.x;
  int wv = tid >> 6, l = tid & 63;
  int grp = l >> 4, cl = l & 15;
  size_t coff = (size_t)cl * 8;
  const int mint = flags[1];
  const void* mraw = flags[2] ? Araw : Braw;
  const unsigned char* m8 = (const unsigned char*)mraw;
  const int* m32 = (const int*)mraw;
  int s = gstart[gid], e = gstart[gid + 1];

  float ex[8], nx[8];
  #pragma unroll
  for (int j = 0; j < 8; j++) { ex[j] = 0.f; nx[j] = 0.f; }
  int ec = 0;

  for (int n = s + wv * 4 + grp; n < e; n += 16) {
    pack16 r;
    r.v = *(const float4*)(o2 + (size_t)n * HID + coff);
    float2 f0 = __half22float2(r.h2[0]);
    float2 f1 = __half22float2(r.h2[1]);
    float2 f2 = __half22float2(r.h2[2]);
    float2 f3 = __half22float2(r.h2[3]);
    float t0 = f0.x, t1 = f0.y, t2 = f1.x, t3 = f1.y;
    float t4 = f2.x, t5 = f2.y, t6 = f3.x, t7 = f3.y;
    nx[0] += t0; nx[1] += t1; nx[2] += t2; nx[3] += t3;
    nx[4] += t4; nx[5] += t5; nx[6] += t6; nx[7] += t7;
    bool mv = mint ? (m32[n] != 0) : (m8[n] != 0);
    if (mv) {
      ex[0] += t0; ex[1] += t1; ex[2] += t2; ex[3] += t3;
      ex[4] += t4; ex[5] += t5; ex[6] += t6; ex[7] += t7;
      ec++;
    }
  }
  #pragma unroll
  for (int j = 0; j < 8; j++) {
    ex[j] += __shfl_xor(ex[j], 16); ex[j] += __shfl_xor(ex[j], 32);
    nx[j] += __shfl_xor(nx[j], 16); nx[j] += __shfl_xor(nx[j], 32);
  }
  ec += __shfl_xor(ec, 16); ec += __shfl_xor(ec, 32);

  if (grp == 0) {
    #pragma unroll
    for (int j = 0; j < 8; j++) { lex[wv][cl * 8 + j] = ex[j]; lnx[wv][cl * 8 + j] = nx[j]; }
    if (cl == 0) lec[wv] = ec;
  }
  __syncthreads();
  if (tid < HID) {
    float exT = lex[0][tid] + lex[1][tid] + lex[2][tid] + lex[3][tid];
    float nxT = lnx[0][tid] + lnx[1][tid] + lnx[2][tid] + lnx[3][tid];
    int ecT = lec[0] + lec[1] + lec[2] + lec[3];
    int cnt = e - s;
    float dv;
    if (ecT > 0) dv = exT / ((float)ecT + 1e-6f);
    else dv = (cnt > 0) ? nxT / (float)cnt : 0.f;
    ldoc[tid] = dv;
  }
  __syncthreads();
  if (tid < 64) {
    float logit = -1e30f;
    if (tid < NC) {
      float acc = bout[tid];
      for (int k = 0; k < HID; k++) acc += ldoc[k] * Wout[k * NC + tid];
      logit = acc;
    }
    float m = logit;
    for (int off = 32; off; off >>= 1) m = fmaxf(m, __shfl_xor(m, off));
    float exv = (tid < NC) ? expf(logit - m) : 0.f;
    float ssum = exv;
    for (int off = 32; off; off >>= 1) ssum += __shfl_xor(ssum, off);
    if (tid < NC) out[gid * NC + tid] = (logit - m) - logf(ssum);
  }
}

__global__ void k_fail(float* __restrict__ out, float enc) {
  int i = blockIdx.x * blockDim.x + threadIdx.x;
  if (i < NG * NC) out[i] = -enc;
}

// ================= launch =================

extern "C" void kernel_launch(void* const* d_in, const int* in_sizes, int n_in,
                              void* d_out, int out_size, void* d_ws, size_t ws_size,
                              hipStream_t stream) {
  int ix = -1, iei = -1, iA = -1, iB = -1, iW1 = -1, ib1 = -1, iW2 = -1, ib2 = -1, iWo = -1, ibo = -1;
  for (int i = 0; i < n_in; i++) {
    int s = in_sizes[i];
    if (s == 30000000) ix = i;
    else if (s == 3200000) iei = i;
    else if (s == 100000) { if (iA < 0) iA = i; else iB = i; }
    else if (s == 38400) iW1 = i;
    else if (s == 16384) iW2 = i;
    else if (s == 2560) iWo = i;
    else if (s == 20) ibo = i;
    else if (s == 128) { if (ib1 < 0) ib1 = i; else ib2 = i; }
  }
  float* out = (float*)d_out;
  int miss = -1;
  if (ix < 0) miss = 0; else if (iei < 0) miss = 1; else if (iA < 0 || iB < 0) miss = 2;
  else if (iW1 < 0) miss = 3; else if (ib1 < 0 || ib2 < 0) miss = 4; else if (iW2 < 0) miss = 5;
  else if (iWo < 0) miss = 6; else if (ibo < 0) miss = 7;
  if (miss >= 0) {
    k_fail<<<(NG * NC + 255) / 256, 256, 0, stream>>>(out, 8192.f + 64.f * (float)miss);
    return;
  }
  const void* x = d_in[ix];
  const int* e32 = (const int*)d_in[iei];
  const void* Araw = d_in[iA];
  const void* Braw = d_in[iB];
  const float* W1 = (const float*)d_in[iW1];
  const float* b1 = (const float*)d_in[ib1];
  const float* W2 = (const float*)d_in[iW2];
  const float* b2 = (const float*)d_in[ib2];
  const float* Wout = (const float*)d_in[iWo];
  const float* bout = (const float*)d_in[ibo];

  char* ws = (char*)d_ws;
  size_t off = 0;
  auto alloc = [&](size_t bytes) -> char* {
    char* p = ws + off; off += (bytes + 255) & ~(size_t)255; return p;
  };
  float* dinv   = (float*)alloc((size_t)NN * 4);
  int* row_off  = (int*)alloc((size_t)(NN + 1) * 4);
  int* csr      = (int*)alloc((size_t)NE * 4);
  int* bcnt     = (int*)alloc((size_t)NBK * 4);
  int* boff     = (int*)alloc((size_t)(NBK + 1) * 4);
  int* bcur     = (int*)alloc((size_t)NBK * 4);
  int* gstart   = (int*)alloc((size_t)(NG + 1) * 4);
  int* flags    = (int*)alloc(8 * 4);
  _Float16* w1f = (_Float16*)alloc(40960 * 2);
  _Float16* w2f = (_Float16*)alloc(16384 * 2);
  __half* gbuf  = (__half*)alloc((size_t)NN * HID * 2);
  __half* obuf  = (__half*)alloc((size_t)NN * HID * 2);
  float* doc    = (float*)alloc((size_t)NG * HID * 4);
  unsigned* diag = (unsigned*)alloc(64 * 4);
  unsigned* ebuf = (unsigned*)gbuf;   // overlay: dead before gemm1 writes gbuf

  hipMemsetAsync(diag, 0, 64 * 4, stream);

  k_probe<<<326, 256, 0, stream>>>((const unsigned short*)x, (const unsigned*)Araw,
                                   (const unsigned*)Braw, e32, W1, W2, w1f, w2f, diag);
  k_setup<<<1, 576, 0, stream>>>(diag, flags, (const int*)Araw, (const int*)Braw, bcnt, gstart);

  k_bhist<<<1024, 256, 0, stream>>>(e32, flags, bcnt, boff, bcur, &diag[32]);
  k_bscatter<<<(NE + BCH - 1) / BCH, 256, 0, stream>>>(e32, flags, bcur, ebuf);
  k_bfinal<<<NBK, 256, 0, stream>>>(ebuf, boff, row_off, dinv, csr);

  // network
  k_gemm1_mfma<<<(NN + 63) / 64, 512, 0, stream>>>(x, w1f, dinv, flags, gbuf);
  k_agg<<<NN / 4, 256, 0, stream>>>(gbuf, dinv, row_off, csr, b1, obuf);
  k_gemm2_mfma<<<(NN + 63) / 64, 256, 0, stream>>>(obuf, w2f, dinv, gbuf);
  k_agg<<<NN / 4, 256, 0, stream>>>(gbuf, dinv, row_off, csr, b2, obuf);

  k_pool<<<NG, 256, 0, stream>>>(obuf, Araw, Braw, gstart, flags, Wout, bout, out);
}

// Round 27
// 297.001 us; speedup vs baseline: 1.2778x; 1.1608x over previous
//
#include <hip/hip_runtime.h>
#include <hip/hip_fp16.h>

#define NN 100000
#define NE 1600000
#define DIM 300
#define HID 128
#define NC 20
#define NG 512
#define NBK 196        // buckets of 512 nodes
#define BCH 8192       // edges per scatter chunk
#define NHB 256        // histogram blocks

typedef _Float16 h8 __attribute__((ext_vector_type(8)));
typedef float f4 __attribute__((ext_vector_type(4)));

union pack16 { float4 v; __half2 h2[4]; };

__device__ __forceinline__ __half tohalf(float v) {
  if (!(v == v)) v = 0.f;
  v = fminf(fmaxf(v, -60000.f), 60000.f);
  return __float2half(v);
}

__device__ __forceinline__ float load_x(const void* xraw, size_t o, int mode) {
  float v;
  if (mode == 2) v = ((const float*)xraw)[o];
  else {
    unsigned short u = ((const unsigned short*)xraw)[o];
    if (mode == 1) { union { unsigned w; float f; } c; c.w = ((unsigned)u) << 16; v = c.f; }
    else { union { unsigned short s; _Float16 h; } c; c.s = u; v = (float)c.h; }
  }
  if (!(v == v)) v = 0.f;
  return fminf(fmaxf(v, -1e4f), 1e4f);
}

__device__ __forceinline__ void cvt4(const void* Ain, size_t off, int mode, _Float16* o) {
  if (mode == 2) {
    float4 fv = *(const float4*)((const float*)Ain + off);
    o[0] = (_Float16)fv.x; o[1] = (_Float16)fv.y; o[2] = (_Float16)fv.z; o[3] = (_Float16)fv.w;
  } else {
    uint2 u = *(const uint2*)((const unsigned short*)Ain + off);
    unsigned short s0 = u.x & 0xFFFF, s1 = u.x >> 16, s2 = u.y & 0xFFFF, s3 = u.y >> 16;
    if (mode == 1) {
      union { unsigned w; float f; } c0, c1, c2, c3;
      c0.w = ((unsigned)s0) << 16; c1.w = ((unsigned)s1) << 16;
      c2.w = ((unsigned)s2) << 16; c3.w = ((unsigned)s3) << 16;
      o[0] = (_Float16)c0.f; o[1] = (_Float16)c1.f; o[2] = (_Float16)c2.f; o[3] = (_Float16)c3.f;
    } else {
      union { unsigned short s; _Float16 h; } d0, d1, d2, d3;
      d0.s = s0; d1.s = s1; d2.s = s2; d3.s = s3;
      o[0] = d0.h; o[1] = d1.h; o[2] = d2.h; o[3] = d3.h;
    }
  }
}

// ============ merged probe + weight-prep kernel ============

__global__ void k_probe(const unsigned short* __restrict__ xu,
                        const unsigned* __restrict__ Araw, const unsigned* __restrict__ Braw,
                        const int* __restrict__ e32,
                        const float* __restrict__ W1, const float* __restrict__ W2,
                        _Float16* __restrict__ w1f, _Float16* __restrict__ w2f,
                        unsigned* __restrict__ diag) {
  int b = blockIdx.x, t = threadIdx.x;
  if (b < 96) {
    int mode = b % 3, chunk = b / 3;
    float m = 0.f;
    if (mode == 0) {
      int base = chunk * 16384;
      for (int j = t; j < 16384; j += 256) {
        union { unsigned short s; _Float16 h; } c; c.s = xu[base + j];
        float v = fabsf((float)c.h);
        if (v == v && v < 65000.f) m = fmaxf(m, v);
      }
    } else if (mode == 1) {
      int base = chunk * 16384;
      for (int j = t; j < 16384; j += 256) {
        union { unsigned w; float f; } c; c.w = ((unsigned)xu[base + j]) << 16;
        float v = fabsf(c.f);
        if (v == v && v < 1e30f) m = fmaxf(m, v);
      }
    } else {
      const float* xf = (const float*)xu;
      int base = chunk * 8192;
      for (int j = t; j < 8192; j += 256) {
        float v = fabsf(xf[base + j]);
        if (v == v && v < 1e30f) m = fmaxf(m, v);
      }
    }
    for (int off = 32; off; off >>= 1) m = fmaxf(m, __shfl_xor(m, off));
    if ((t & 63) == 0) atomicMax(&diag[20 + mode], __float_as_uint(m));
  } else if (b == 96 || b == 97) {
    __shared__ unsigned red[256];
    const unsigned* p = (b == 96) ? Araw : Braw;
    unsigned m = 0;
    for (int j = t; j < 25000; j += 256) m = max(m, p[j]);
    red[t] = m; __syncthreads();
    for (int off = 128; off; off >>= 1) { if (t < off) red[t] = max(red[t], red[t + off]); __syncthreads(); }
    if (t == 0) diag[(b == 96) ? 24 : 25] = red[0];
  } else if (b < 102) {
    int i = (b - 98) * 256 + t;
    unsigned z = 0;
    for (; i < 50000; i += 1024) if (e32[2 * i + 1] == 0) z++;
    for (int off = 32; off; off >>= 1) z += __shfl_xor(z, off);
    if ((t & 63) == 0) atomicAdd(&diag[26], z);
  } else {
    int idx = (b - 102) * 256 + t;
    const int S1 = 10 * 8 * 64 * 8;  // 40960
    const int S2 = 4 * 8 * 64 * 8;   // 16384
    if (idx < S1) {
      int j = idx & 7, l = (idx >> 3) & 63, nt = (idx >> 9) & 7, kc = idx >> 12;
      int k = kc * 32 + ((l >> 4) << 3) + j;
      int n = nt * 16 + (l & 15);
      w1f[idx] = (k < DIM) ? (_Float16)W1[k * HID + n] : (_Float16)0.f;
    } else if (idx < S1 + S2) {
      int q = idx - S1;
      int j = q & 7, l = (q >> 3) & 63, nt = (q >> 9) & 7, kc = q >> 12;
      int k = kc * 32 + ((l >> 4) << 3) + j;
      int n = nt * 16 + (l & 15);
      w2f[q] = (_Float16)W2[k * HID + n];
    }
  }
}

// ============ merged setup: decide flags + gstart ============

__global__ void k_setup(const unsigned* __restrict__ diag, int* __restrict__ flags,
                        const int* __restrict__ A, const int* __restrict__ B,
                        int* __restrict__ gstart) {
  __shared__ int sflags[8];
  int t = threadIdx.x;
  if (t == 0) {
    float M16 = __uint_as_float(diag[20]);
    float M32 = __uint_as_float(diag[21]);
    float Mf  = __uint_as_float(diag[22]);
    int xmode = 3;
    if      (Mf  > 3.f && Mf  < 8.f) xmode = 2;
    else if (M32 > 3.f && M32 < 8.f) xmode = 1;
    else if (M16 > 3.f && M16 < 8.f) xmode = 0;
    unsigned uA = diag[24], uB = diag[25];
    bool Ab = (uA >= 32u && uA < 1024u), Bb = (uB >= 32u && uB < 1024u);
    int swap = -1;
    if (Ab && !Bb) swap = 0;
    else if (Bb && !Ab) swap = 1;
    int mint = -1;
    if (swap >= 0) {
      unsigned um = (swap == 0) ? uB : uA;
      if (um <= 1u) mint = 1;
      else if (um >= 65536u) mint = 0;
    }
    sflags[0] = xmode;
    sflags[1] = (mint == 1) ? 1 : 0;
    sflags[2] = (swap == 1) ? 1 : 0;
    sflags[3] = (diag[26] >= 49990u) ? 1 : 0;
    sflags[4] = (swap >= 0 && mint >= 0) ? 1 : 0;
    #pragma unroll
    for (int j = 0; j < 5; j++) flags[j] = sflags[j];
  }
  __syncthreads();
  const int* batch = sflags[2] ? B : A;
  if (t <= NG) {
    if (t == NG) gstart[NG] = NN;
    else {
      int lo = 0, hi = NN;
      while (lo < hi) { int mid = (lo + hi) >> 1; if (batch[mid] < t) lo = mid + 1; else hi = mid; }
      gstart[t] = lo;
    }
  }
}

// ================= bucketed CSR build: atomic-free histogram =================
// each block writes its private 196-entry histogram to hist2d[b][*] (no atomics).

__global__ __launch_bounds__(256)
void k_bhist(const int* __restrict__ e32, const int* __restrict__ flags,
             int* __restrict__ hist2d) {
  __shared__ int hist[NBK];
  int e64 = flags[3];
  int b = blockIdx.x, t = threadIdx.x;
  for (int j = t; j < NBK; j += 256) hist[j] = 0;
  __syncthreads();
  int i = b * blockDim.x + t;
  int stride = gridDim.x * blockDim.x;
  for (; i < NE; i += stride) {
    int s = e64 ? e32[2 * i] : e32[i];
    int d = e64 ? e32[2 * NE + 2 * i] : e32[NE + i];
    if ((unsigned)s < (unsigned)NN && (unsigned)d < (unsigned)NN)
      atomicAdd(&hist[d >> 9], 1);
  }
  __syncthreads();
  for (int j = t; j < NBK; j += 256) hist2d[b * NBK + j] = hist[j];
}

// 1 block: column-sum hist2d + prefix -> boff, bcur
__global__ __launch_bounds__(256)
void k_bscan(const int* __restrict__ hist2d, int* __restrict__ boff, int* __restrict__ bcur) {
  __shared__ int sums[NBK];
  int t = threadIdx.x;
  if (t < NBK) {
    int s = 0;
    for (int b = 0; b < NHB; b++) s += hist2d[b * NBK + t];
    sums[t] = s;
  }
  __syncthreads();
  if (t == 0) {
    int run = 0;
    for (int j = 0; j < NBK; j++) { boff[j] = run; bcur[j] = run; run += sums[j]; }
    boff[NBK] = run;
  }
}

__global__ __launch_bounds__(256)
void k_bscatter(const int* __restrict__ e32, const int* __restrict__ flags,
                int* __restrict__ bcur, unsigned* __restrict__ ebuf) {
  __shared__ uint2 stage[BCH];           // 64 KB
  __shared__ int hist[NBK];
  __shared__ int lbase[NBK];
  __shared__ int lcur[NBK];
  int e64 = flags[3];
  int t = threadIdx.x;
  for (int j = t; j < NBK; j += 256) { hist[j] = 0; lcur[j] = 0; }
  __syncthreads();
  int start = blockIdx.x * BCH;
  int n = NE - start; if (n > BCH) n = BCH;
  for (int i = t; i < n; i += 256) {
    int idx = start + i;
    int s = e64 ? e32[2 * idx] : e32[idx];
    int d = e64 ? e32[2 * NE + 2 * idx] : e32[NE + idx];
    bool ok = ((unsigned)s < (unsigned)NN) && ((unsigned)d < (unsigned)NN);
    stage[i] = make_uint2(ok ? (unsigned)s : 0xFFFFFFFFu, (unsigned)(ok ? d : 0));
    if (ok) atomicAdd(&hist[d >> 9], 1);
  }
  __syncthreads();
  for (int j = t; j < NBK; j += 256) if (hist[j] > 0) lbase[j] = atomicAdd(&bcur[j], hist[j]);
  __syncthreads();
  for (int i = t; i < n; i += 256) {
    unsigned s = stage[i].x;
    if (s == 0xFFFFFFFFu) continue;
    int d = (int)stage[i].y;
    int b = d >> 9;
    int o = atomicAdd(&lcur[b], 1);
    ebuf[lbase[b] + o] = (s << 9) | (unsigned)(d & 511);
  }
}

__global__ __launch_bounds__(256)
void k_bfinal(const unsigned* __restrict__ ebuf, const int* __restrict__ boff,
              int* __restrict__ row_off, float* __restrict__ dinv, int* __restrict__ csr) {
  __shared__ int ldeg[512];
  __shared__ int lcur[512];
  int b = blockIdx.x, t = threadIdx.x;
  int base = b * 512;
  int nn = NN - base; if (nn > 512) nn = 512;
  for (int j = t; j < 512; j += 256) ldeg[j] = 0;
  __syncthreads();
  int s0 = boff[b], s1 = boff[b + 1];
  for (int e = s0 + t; e < s1; e += 256) atomicAdd(&ldeg[ebuf[e] & 511], 1);
  __syncthreads();
  if (t == 0) {
    int run = s0;
    for (int i = 0; i < nn; i++) { lcur[i] = run; row_off[base + i] = run; run += ldeg[i]; }
    if (b == gridDim.x - 1) row_off[NN] = run;
  }
  __syncthreads();
  for (int j = t; j < nn; j += 256) dinv[base + j] = rsqrtf((float)ldeg[j] + 1.0f);
  for (int e = s0 + t; e < s1; e += 256) {
    unsigned v = ebuf[e];
    int p = atomicAdd(&lcur[v & 511], 1);
    csr[p] = (int)(v >> 9);
  }
}

// ============ GEMM1: 512-thread blocks (8 waves, 1 nt each), two-pass K-split ============

#define XS1 168

__global__ __launch_bounds__(512)
void k_gemm1_mfma(const void* __restrict__ Ain, const _Float16* __restrict__ bfrag,
                  const float* __restrict__ dinv, const int* __restrict__ flags,
                  __half* __restrict__ outg) {
  __shared__ _Float16 xs[64 * XS1];   // 21504 B
  const int mode = flags[0] & 3;
  int tid = threadIdx.x;
  int w = tid >> 6, l = tid & 63;
  int rowbase = blockIdx.x * 64;
  int k0base = (l >> 4) << 3;
  int cb = l & 15;

  f4 acc[4];
  f4 zero = {0.f, 0.f, 0.f, 0.f};
  #pragma unroll
  for (int rg = 0; rg < 4; rg++) acc[rg] = zero;

  #pragma unroll
  for (int it = 0; it < 5; it++) {
    int c = tid + it * 512;
    int rl = c / 40, kk = (c - rl * 40) * 4;
    int r = rowbase + rl;
    _Float16 o[4] = {0, 0, 0, 0};
    if (r < NN) cvt4(Ain, (size_t)r * DIM + kk, mode, o);
    _Float16* p = &xs[rl * XS1 + kk];
    p[0] = o[0]; p[1] = o[1]; p[2] = o[2]; p[3] = o[3];
  }
  __syncthreads();
  #pragma unroll
  for (int kc = 0; kc < 5; kc++) {
    int ko = kc * 32 + k0base;
    h8 a0 = *(const h8*)&xs[(0 * 16 + cb) * XS1 + ko];
    h8 a1 = *(const h8*)&xs[(1 * 16 + cb) * XS1 + ko];
    h8 a2 = *(const h8*)&xs[(2 * 16 + cb) * XS1 + ko];
    h8 a3 = *(const h8*)&xs[(3 * 16 + cb) * XS1 + ko];
    h8 bv = *(const h8*)&bfrag[(((kc << 3) + w) * 64 + l) * 8];
    acc[0] = __builtin_amdgcn_mfma_f32_16x16x32_f16(a0, bv, acc[0], 0, 0, 0);
    acc[1] = __builtin_amdgcn_mfma_f32_16x16x32_f16(a1, bv, acc[1], 0, 0, 0);
    acc[2] = __builtin_amdgcn_mfma_f32_16x16x32_f16(a2, bv, acc[2], 0, 0, 0);
    acc[3] = __builtin_amdgcn_mfma_f32_16x16x32_f16(a3, bv, acc[3], 0, 0, 0);
  }
  __syncthreads();

  for (int t2 = tid; t2 < 64 * 10; t2 += 512) {
    int rl = t2 / 10, j = t2 - rl * 10;
    *(unsigned*)&xs[rl * XS1 + 140 + j * 2] = 0u;
  }
  #pragma unroll
  for (int it = 0; it < 5; it++) {
    int c = tid + it * 512;
    if (c < 64 * 35) {
      int rl = c / 35, kk = (c - rl * 35) * 4;
      int r = rowbase + rl;
      _Float16 o[4] = {0, 0, 0, 0};
      if (r < NN) cvt4(Ain, (size_t)r * DIM + 160 + kk, mode, o);
      _Float16* p = &xs[rl * XS1 + kk];
      p[0] = o[0]; p[1] = o[1]; p[2] = o[2]; p[3] = o[3];
    }
  }
  __syncthreads();
  #pragma unroll
  for (int kc = 5; kc < 10; kc++) {
    int ko = (kc - 5) * 32 + k0base;
    h8 a0 = *(const h8*)&xs[(0 * 16 + cb) * XS1 + ko];
    h8 a1 = *(const h8*)&xs[(1 * 16 + cb) * XS1 + ko];
    h8 a2 = *(const h8*)&xs[(2 * 16 + cb) * XS1 + ko];
    h8 a3 = *(const h8*)&xs[(3 * 16 + cb) * XS1 + ko];
    h8 bv = *(const h8*)&bfrag[(((kc << 3) + w) * 64 + l) * 8];
    acc[0] = __builtin_amdgcn_mfma_f32_16x16x32_f16(a0, bv, acc[0], 0, 0, 0);
    acc[1] = __builtin_amdgcn_mfma_f32_16x16x32_f16(a1, bv, acc[1], 0, 0, 0);
    acc[2] = __builtin_amdgcn_mfma_f32_16x16x32_f16(a2, bv, acc[2], 0, 0, 0);
    acc[3] = __builtin_amdgcn_mfma_f32_16x16x32_f16(a3, bv, acc[3], 0, 0, 0);
  }

  int rquad = (l >> 4) << 2;
  #pragma unroll
  for (int rg = 0; rg < 4; rg++) {
    #pragma unroll
    for (int i = 0; i < 4; i++) {
      int r = rowbase + rg * 16 + rquad + i;
      if (r >= NN) continue;
      float dv = dinv[r];
      outg[(size_t)r * HID + w * 16 + cb] = tohalf(acc[rg][i] * dv);
    }
  }
}

// ============ GEMM2: batched staging + nt-pair waves ============

__global__ __launch_bounds__(256)
void k_gemm2_mfma(const __half* __restrict__ Ain, const _Float16* __restrict__ bfrag,
                  const float* __restrict__ dinv, __half* __restrict__ outg) {
  __shared__ _Float16 xs[64 * 136];
  int tid = threadIdx.x;
  int w = tid >> 6, l = tid & 63;
  int rowbase = blockIdx.x * 64;
  int k0base = (l >> 4) << 3;
  int cb = l & 15;

  {
    h8 regs[4];
    #pragma unroll
    for (int it = 0; it < 4; it++) {
      int c = tid + it * 256;
      int rl = c >> 4, k = (c & 15) * 8;
      int r = rowbase + rl;
      h8 v = {};
      if (r < NN) v = *(const h8*)((const _Float16*)Ain + (size_t)r * HID + k);
      regs[it] = v;
    }
    __builtin_amdgcn_sched_barrier(0);
    #pragma unroll
    for (int it = 0; it < 4; it++) {
      int c = tid + it * 256;
      int rl = c >> 4, k = (c & 15) * 8;
      *(h8*)&xs[rl * 136 + k] = regs[it];
    }
  }
  __syncthreads();

  f4 acc[4][2];
  f4 zero = {0.f, 0.f, 0.f, 0.f};
  #pragma unroll
  for (int rg = 0; rg < 4; rg++) { acc[rg][0] = zero; acc[rg][1] = zero; }

  #pragma unroll
  for (int kc = 0; kc < 4; kc++) {
    int ko = kc * 32 + k0base;
    h8 a0 = *(const h8*)&xs[(0 * 16 + cb) * 136 + ko];
    h8 a1 = *(const h8*)&xs[(1 * 16 + cb) * 136 + ko];
    h8 a2 = *(const h8*)&xs[(2 * 16 + cb) * 136 + ko];
    h8 a3 = *(const h8*)&xs[(3 * 16 + cb) * 136 + ko];
    #pragma unroll
    for (int ntl = 0; ntl < 2; ntl++) {
      int nt = w * 2 + ntl;
      h8 bv = *(const h8*)&bfrag[(((kc << 3) + nt) * 64 + l) * 8];
      acc[0][ntl] = __builtin_amdgcn_mfma_f32_16x16x32_f16(a0, bv, acc[0][ntl], 0, 0, 0);
      acc[1][ntl] = __builtin_amdgcn_mfma_f32_16x16x32_f16(a1, bv, acc[1][ntl], 0, 0, 0);
      acc[2][ntl] = __builtin_amdgcn_mfma_f32_16x16x32_f16(a2, bv, acc[2][ntl], 0, 0, 0);
      acc[3][ntl] = __builtin_amdgcn_mfma_f32_16x16x32_f16(a3, bv, acc[3][ntl], 0, 0, 0);
    }
  }

  int rquad = (l >> 4) << 2;
  #pragma unroll
  for (int rg = 0; rg < 4; rg++) {
    #pragma unroll
    for (int i = 0; i < 4; i++) {
      int r = rowbase + rg * 16 + rquad + i;
      if (r >= NN) continue;
      float dv = dinv[r];
      __half* orow = outg + (size_t)r * HID;
      orow[(w * 2 + 0) * 16 + cb] = tohalf(acc[rg][0][i] * dv);
      orow[(w * 2 + 1) * 16 + cb] = tohalf(acc[rg][1][i] * dv);
    }
  }
}

// ------- aggregation: 4 edges in flight per wave, 16B/lane gathers -------

__global__ __launch_bounds__(256)
void k_agg(const __half* __restrict__ g, const float* __restrict__ dinv,
           const int* __restrict__ row_off, const int* __restrict__ csr,
           const float* __restrict__ bias, __half* __restrict__ out) {
  int tid = threadIdx.x;
  int node = blockIdx.x * 4 + (tid >> 6);
  int l = tid & 63;
  if (node >= NN) return;
  int grp = l >> 4;
  int cl  = l & 15;
  size_t coff = (size_t)cl * 8;

  float a0 = 0.f, a1 = 0.f, a2 = 0.f, a3 = 0.f, a4 = 0.f, a5 = 0.f, a6 = 0.f, a7 = 0.f;
  pack16 r;

  #define ACCUM() do { \
    float2 f0 = __half22float2(r.h2[0]); \
    float2 f1 = __half22float2(r.h2[1]); \
    float2 f2 = __half22float2(r.h2[2]); \
    float2 f3 = __half22float2(r.h2[3]); \
    a0 += f0.x; a1 += f0.y; a2 += f1.x; a3 += f1.y; \
    a4 += f2.x; a5 += f2.y; a6 += f3.x; a7 += f3.y; } while (0)

  int e0 = row_off[node], e1 = row_off[node + 1];
  int e = e0 + grp;
  for (; e + 4 < e1; e += 8) {
    int s1 = csr[e], s2 = csr[e + 4];
    pack16 rA, rB;
    rA.v = *(const float4*)(g + (size_t)s1 * HID + coff);
    rB.v = *(const float4*)(g + (size_t)s2 * HID + coff);
    r = rA; ACCUM();
    r = rB; ACCUM();
  }
  if (e < e1) {
    int s1 = csr[e];
    r.v = *(const float4*)(g + (size_t)s1 * HID + coff);
    ACCUM();
  }
  if (grp == 0) {
    r.v = *(const float4*)(g + (size_t)node * HID + coff);
    ACCUM();
  }
  #undef ACCUM

  a0 += __shfl_xor(a0, 16); a1 += __shfl_xor(a1, 16); a2 += __shfl_xor(a2, 16); a3 += __shfl_xor(a3, 16);
  a4 += __shfl_xor(a4, 16); a5 += __shfl_xor(a5, 16); a6 += __shfl_xor(a6, 16); a7 += __shfl_xor(a7, 16);
  a0 += __shfl_xor(a0, 32); a1 += __shfl_xor(a1, 32); a2 += __shfl_xor(a2, 32); a3 += __shfl_xor(a3, 32);
  a4 += __shfl_xor(a4, 32); a5 += __shfl_xor(a5, 32); a6 += __shfl_xor(a6, 32); a7 += __shfl_xor(a7, 32);

  if (grp == 0) {
    float di = dinv[node];
    const float* bp = bias + coff;
    pack16 w;
    w.h2[0] = __floats2half2_rn(fmaxf(a0 * di + bp[0], 0.f), fmaxf(a1 * di + bp[1], 0.f));
    w.h2[1] = __floats2half2_rn(fmaxf(a2 * di + bp[2], 0.f), fmaxf(a3 * di + bp[3], 0.f));
    w.h2[2] = __floats2half2_rn(fmaxf(a4 * di + bp[4], 0.f), fmaxf(a5 * di + bp[5], 0.f));
    w.h2[3] = __floats2half2_rn(fmaxf(a6 * di + bp[6], 0.f), fmaxf(a7 * di + bp[7], 0.f));
    *(float4*)(out + (size_t)node * HID + coff) = w.v;
  }
}

// ------- pooling + head fused: one graph per 256-thr block -------

__global__ __launch_bounds__(256)
void k_pool(const __half* __restrict__ o2, const void* __restrict__ Araw, const void* __restrict__ Braw,
            const int* __restrict__ gstart, const int* __restrict__ flags,
            const float* __restrict__ Wout, const float* __restrict__ bout,
            float* __restrict__ out) {
  __shared__ float lex[4][HID];
  __shared__ float lnx[4][HID];
  __shared__ int lec[4];
  __shared__ float ldoc[HID];
  int gid = blockIdx.x, tid = threadIdx.x;
  int wv = tid >> 6, l = tid & 63;
  int grp = l >> 4, cl = l & 15;
  size_t coff = (size_t)cl * 8;
  const int mint = flags[1];
  const void* mraw = flags[2] ? Araw : Braw;
  const unsigned char* m8 = (const unsigned char*)mraw;
  const int* m32 = (const int*)mraw;
  int s = gstart[gid], e = gstart[gid + 1];

  float ex[8], nx[8];
  #pragma unroll
  for (int j = 0; j < 8; j++) { ex[j] = 0.f; nx[j] = 0.f; }
  int ec = 0;

  for (int n = s + wv * 4 + grp; n < e; n += 16) {
    pack16 r;
    r.v = *(const float4*)(o2 + (size_t)n * HID + coff);
    float2 f0 = __half22float2(r.h2[0]);
    float2 f1 = __half22float2(r.h2[1]);
    float2 f2 = __half22float2(r.h2[2]);
    float2 f3 = __half22float2(r.h2[3]);
    float t0 = f0.x, t1 = f0.y, t2 = f1.x, t3 = f1.y;
    float t4 = f2.x, t5 = f2.y, t6 = f3.x, t7 = f3.y;
    nx[0] += t0; nx[1] += t1; nx[2] += t2; nx[3] += t3;
    nx[4] += t4; nx[5] += t5; nx[6] += t6; nx[7] += t7;
    bool mv = mint ? (m32[n] != 0) : (m8[n] != 0);
    if (mv) {
      ex[0] += t0; ex[1] += t1; ex[2] += t2; ex[3] += t3;
      ex[4] += t4; ex[5] += t5; ex[6] += t6; ex[7] += t7;
      ec++;
    }
  }
  #pragma unroll
  for (int j = 0; j < 8; j++) {
    ex[j] += __shfl_xor(ex[j], 16); ex[j] += __shfl_xor(ex[j], 32);
    nx[j] += __shfl_xor(nx[j], 16); nx[j] += __shfl_xor(nx[j], 32);
  }
  ec += __shfl_xor(ec, 16); ec += __shfl_xor(ec, 32);

  if (grp == 0) {
    #pragma unroll
    for (int j = 0; j < 8; j++) { lex[wv][cl * 8 + j] = ex[j]; lnx[wv][cl * 8 + j] = nx[j]; }
    if (cl == 0) lec[wv] = ec;
  }
  __syncthreads();
  if (tid < HID) {
    float exT = lex[0][tid] + lex[1][tid] + lex[2][tid] + lex[3][tid];
    float nxT = lnx[0][tid] + lnx[1][tid] + lnx[2][tid] + lnx[3][tid];
    int ecT = lec[0] + lec[1] + lec[2] + lec[3];
    int cnt = e - s;
    float dv;
    if (ecT > 0) dv = exT / ((float)ecT + 1e-6f);
    else dv = (cnt > 0) ? nxT / (float)cnt : 0.f;
    ldoc[tid] = dv;
  }
  __syncthreads();
  if (tid < 64) {
    float logit = -1e30f;
    if (tid < NC) {
      float acc = bout[tid];
      for (int k = 0; k < HID; k++) acc += ldoc[k] * Wout[k * NC + tid];
      logit = acc;
    }
    float m = logit;
    for (int off = 32; off; off >>= 1) m = fmaxf(m, __shfl_xor(m, off));
    float exv = (tid < NC) ? expf(logit - m) : 0.f;
    float ssum = exv;
    for (int off = 32; off; off >>= 1) ssum += __shfl_xor(ssum, off);
    if (tid < NC) out[gid * NC + tid] = (logit - m) - logf(ssum);
  }
}

__global__ void k_fail(float* __restrict__ out, float enc) {
  int i = blockIdx.x * blockDim.x + threadIdx.x;
  if (i < NG * NC) out[i] = -enc;
}

// ================= launch =================

extern "C" void kernel_launch(void* const* d_in, const int* in_sizes, int n_in,
                              void* d_out, int out_size, void* d_ws, size_t ws_size,
                              hipStream_t stream) {
  int ix = -1, iei = -1, iA = -1, iB = -1, iW1 = -1, ib1 = -1, iW2 = -1, ib2 = -1, iWo = -1, ibo = -1;
  for (int i = 0; i < n_in; i++) {
    int s = in_sizes[i];
    if (s == 30000000) ix = i;
    else if (s == 3200000) iei = i;
    else if (s == 100000) { if (iA < 0) iA = i; else iB = i; }
    else if (s == 38400) iW1 = i;
    else if (s == 16384) iW2 = i;
    else if (s == 2560) iWo = i;
    else if (s == 20) ibo = i;
    else if (s == 128) { if (ib1 < 0) ib1 = i; else ib2 = i; }
  }
  float* out = (float*)d_out;
  int miss = -1;
  if (ix < 0) miss = 0; else if (iei < 0) miss = 1; else if (iA < 0 || iB < 0) miss = 2;
  else if (iW1 < 0) miss = 3; else if (ib1 < 0 || ib2 < 0) miss = 4; else if (iW2 < 0) miss = 5;
  else if (iWo < 0) miss = 6; else if (ibo < 0) miss = 7;
  if (miss >= 0) {
    k_fail<<<(NG * NC + 255) / 256, 256, 0, stream>>>(out, 8192.f + 64.f * (float)miss);
    return;
  }
  const void* x = d_in[ix];
  const int* e32 = (const int*)d_in[iei];
  const void* Araw = d_in[iA];
  const void* Braw = d_in[iB];
  const float* W1 = (const float*)d_in[iW1];
  const float* b1 = (const float*)d_in[ib1];
  const float* W2 = (const float*)d_in[iW2];
  const float* b2 = (const float*)d_in[ib2];
  const float* Wout = (const float*)d_in[iWo];
  const float* bout = (const float*)d_in[ibo];

  char* ws = (char*)d_ws;
  size_t off = 0;
  auto alloc = [&](size_t bytes) -> char* {
    char* p = ws + off; off += (bytes + 255) & ~(size_t)255; return p;
  };
  float* dinv   = (float*)alloc((size_t)NN * 4);
  int* row_off  = (int*)alloc((size_t)(NN + 1) * 4);
  int* csr      = (int*)alloc((size_t)NE * 4);
  int* hist2d   = (int*)alloc((size_t)NHB * NBK * 4);
  int* boff     = (int*)alloc((size_t)(NBK + 1) * 4);
  int* bcur     = (int*)alloc((size_t)NBK * 4);
  int* gstart   = (int*)alloc((size_t)(NG + 1) * 4);
  int* flags    = (int*)alloc(8 * 4);
  _Float16* w1f = (_Float16*)alloc(40960 * 2);
  _Float16* w2f = (_Float16*)alloc(16384 * 2);
  __half* gbuf  = (__half*)alloc((size_t)NN * HID * 2);
  __half* obuf  = (__half*)alloc((size_t)NN * HID * 2);
  unsigned* diag = (unsigned*)alloc(64 * 4);
  unsigned* ebuf = (unsigned*)gbuf;   // overlay: dead before gemm1 writes gbuf

  hipMemsetAsync(diag, 0, 64 * 4, stream);

  k_probe<<<326, 256, 0, stream>>>((const unsigned short*)x, (const unsigned*)Araw,
                                   (const unsigned*)Braw, e32, W1, W2, w1f, w2f, diag);
  k_setup<<<1, 576, 0, stream>>>(diag, flags, (const int*)Araw, (const int*)Braw, gstart);

  k_bhist<<<NHB, 256, 0, stream>>>(e32, flags, hist2d);
  k_bscan<<<1, 256, 0, stream>>>(hist2d, boff, bcur);
  k_bscatter<<<(NE + BCH - 1) / BCH, 256, 0, stream>>>(e32, flags, bcur, ebuf);
  k_bfinal<<<NBK, 256, 0, stream>>>(ebuf, boff, row_off, dinv, csr);

  // network
  k_gemm1_mfma<<<(NN + 63) / 64, 512, 0, stream>>>(x, w1f, dinv, flags, gbuf);
  k_agg<<<NN / 4, 256, 0, stream>>>(gbuf, dinv, row_off, csr, b1, obuf);
  k_gemm2_mfma<<<(NN + 63) / 64, 256, 0, stream>>>(obuf, w2f, dinv, gbuf);
  k_agg<<<NN / 4, 256, 0, stream>>>(gbuf, dinv, row_off, csr, b2, obuf);

  k_pool<<<NG, 256, 0, stream>>>(obuf, Araw, Braw, gstart, flags, Wout, bout, out);
}